// Round 4
// baseline (1093.853 us; speedup 1.0000x reference)
//
#include <hip/hip_runtime.h>
#include <hip/hip_bf16.h>

#define N_USERS   50000
#define N_ITEMS   100000
#define N_NODES   150000
#define DIM       64
#define N_INTENTS 128
#define N_EDGES   3000000
#define PSHIFT    9                         // 512 rows per partition
#define PROWS     (1 << PSHIFT)
#define NPART     ((N_NODES + PROWS - 1) >> PSHIFT)   // 293
#define CHUNK     16384                     // edges per binning block
#define NCHB      ((N_EDGES + CHUNK - 1) / CHUNK)     // 184

#define UT_TILES  (N_USERS / 16)            // 3125
#define TOT_TILES ((N_USERS + N_ITEMS) / 16) // 9375
#define INT_B     ((TOT_TILES + 3) / 4)     // 2344 intent blocks
#define FUSED_G   (17 * INT_B)              // 39848; 39848-2344=37504 >= 37500 spmm blocks

typedef __attribute__((ext_vector_type(8))) short short8v;  // 8 bf16 (4 VGPRs)
typedef __attribute__((ext_vector_type(4))) float f32x4;

static __device__ __forceinline__ float wsum64(float v){
#pragma unroll
  for (int m = 32; m >= 1; m >>= 1) v += __shfl_xor(v, m, 64);
  return v;
}

// ---- DPP 16-lane row reduction (full-rate VALU)
template<int CTRL>
static __device__ __forceinline__ float dpp_ror_add(float x){
  int t = __builtin_amdgcn_update_dpp(0, __builtin_bit_cast(int, x),
                                      CTRL, 0xF, 0xF, true);
  return x + __builtin_bit_cast(float, t);
}
static __device__ __forceinline__ float row16_allsum(float x){
  x = dpp_ror_add<0x128>(x);  // row_ror:8
  x = dpp_ror_add<0x124>(x);  // row_ror:4
  x = dpp_ror_add<0x122>(x);  // row_ror:2
  x = dpp_ror_add<0x121>(x);  // row_ror:1
  return x;
}
template<int CTRL>
static __device__ __forceinline__ float dpp_ror_max(float x){
  int t = __builtin_amdgcn_update_dpp(0, __builtin_bit_cast(int, x),
                                      CTRL, 0xF, 0xF, true);
  return fmaxf(x, __builtin_bit_cast(float, t));
}
static __device__ __forceinline__ float row16_allmax(float x){
  x = dpp_ror_max<0x128>(x);
  x = dpp_ror_max<0x124>(x);
  x = dpp_ror_max<0x122>(x);
  x = dpp_ror_max<0x121>(x);
  return x;
}

// bf16 pack/unpack
static __device__ __forceinline__ unsigned short f2bf(float x){
  __hip_bfloat16 h = __float2bfloat16(x);
  return __builtin_bit_cast(unsigned short, h);
}
static __device__ __forceinline__ float bf_lo(unsigned int v){
  return __builtin_bit_cast(float, v << 16);
}
static __device__ __forceinline__ float bf_hi(unsigned int v){
  return __builtin_bit_cast(float, v & 0xFFFF0000u);
}
static __device__ __forceinline__ float bfval(unsigned short h){
  return __builtin_bit_cast(float, (unsigned int)h << 16);
}
// hi/lo bf16 split: x ~= bf(hi) + bf(lo), rel err ~2^-17 (fp32-fidelity for MFMA)
static __device__ __forceinline__ void split2(float x, unsigned short& hi,
                                              unsigned short& lo){
  hi = f2bf(x);
  lo = f2bf(x - bfval(hi));
}

// emb = concat(user_emb, item_emb); acc(=d_out) = emb; embb = bf16(emb)
__global__ void k_init(const float* __restrict__ ue, const float* __restrict__ ie,
                       float* __restrict__ emb, float* __restrict__ acc,
                       unsigned short* __restrict__ embb){
  int i = blockIdx.x * 256 + threadIdx.x;
  if (i >= N_NODES * DIM) return;
  float v = (i < N_USERS * DIM) ? ue[i] : ie[i - N_USERS * DIM];
  emb[i] = v; acc[i] = v; embb[i] = f2bf(v);
}

__global__ void k_deg(const int* __restrict__ h, int* __restrict__ deg){
  int e = blockIdx.x * 256 + threadIdx.x;
  if (e < N_EDGES) atomicAdd(&deg[h[e]], 1);
}

__global__ void k_scan1(const int* __restrict__ deg, int* __restrict__ tmp,
                        int* __restrict__ aux){
  __shared__ int s[256];
  int t = threadIdx.x, i = blockIdx.x * 256 + t;
  int v = (i < N_NODES) ? deg[i] : 0;
  s[t] = v; __syncthreads();
  for (int off = 1; off < 256; off <<= 1){
    int x = (t >= off) ? s[t - off] : 0;
    __syncthreads();
    s[t] += x;
    __syncthreads();
  }
  if (i < N_NODES) tmp[i] = s[t];
  if (t == 255) aux[blockIdx.x] = s[255];
}

__global__ __launch_bounds__(1024) void k_scan2(int* __restrict__ aux, int n){
  __shared__ int s[1024];
  int t = threadIdx.x;
  int v = (t < n) ? aux[t] : 0;
  s[t] = v; __syncthreads();
  for (int off = 1; off < 1024; off <<= 1){
    int x = (t >= off) ? s[t - off] : 0;
    __syncthreads();
    s[t] += x;
    __syncthreads();
  }
  if (t < n) aux[t] = s[t] - v;   // exclusive
}

__global__ void k_rowptr(const int* __restrict__ tmp, const int* __restrict__ deg,
                         const int* __restrict__ aux, int* __restrict__ rp,
                         float* __restrict__ dis, int* __restrict__ gcur){
  int i = blockIdx.x * 256 + threadIdx.x;
  if (i < N_NODES){
    int v = aux[i >> 8] + tmp[i] - deg[i];
    rp[i] = v;
    int d = deg[i];
    dis[i] = (d > 0) ? (1.f / sqrtf((float)d)) : 0.f;
    if ((i & (PROWS - 1)) == 0) gcur[i >> PSHIFT] = v;  // partition append cursor
  }
  if (i == 0) rp[N_NODES] = N_EDGES;
}

// Counting-sort pass 1: per-block LDS histogram over 293 partitions, ONE
// global reservation per (block,partition), then scatter into block-exclusive
// contiguous runs.
__global__ __launch_bounds__(256) void k_part1(const int* __restrict__ h,
                                               const int* __restrict__ t,
                                               int* __restrict__ gcur,
                                               unsigned int* __restrict__ stg){
  __shared__ int hist[NPART];
  __shared__ int base[NPART];
  __shared__ int cnt2[NPART];
  int tid = threadIdx.x;
  int s = blockIdx.x * CHUNK;
  int e = min(s + CHUNK, N_EDGES);
  for (int p = tid; p < NPART; p += 256){ hist[p] = 0; cnt2[p] = 0; }
  __syncthreads();
  for (int i = s + tid; i < e; i += 256)
    atomicAdd(&hist[h[i] >> PSHIFT], 1);
  __syncthreads();
  for (int p = tid; p < NPART; p += 256){
    int c = hist[p];
    base[p] = c ? atomicAdd(&gcur[p], c) : 0;
  }
  __syncthreads();
  for (int i = s + tid; i < e; i += 256){
    int hh = h[i];
    int part = hh >> PSHIFT;
    int pos = base[part] + atomicAdd(&cnt2[part], 1);
    stg[pos] = ((unsigned)t[i] << PSHIFT) | (unsigned)(hh & (PROWS - 1));
  }
}

// Counting-sort pass 2: one block per partition.
__global__ __launch_bounds__(256) void k_part2(const int* __restrict__ rp,
                                               const unsigned int* __restrict__ stg,
                                               int* __restrict__ t_csr){
  __shared__ int cur[PROWS];
  int b = blockIdx.x, tid = threadIdx.x;
  int row0 = b << PSHIFT;
  int rows = min(PROWS, N_NODES - row0);
  for (int i = tid; i < rows; i += 256) cur[i] = rp[row0 + i];
  __syncthreads();
  int s = rp[row0], e = rp[row0 + rows];
  for (int i = s + tid; i < e; i += 256){
    unsigned int v = stg[i];
    int pos = atomicAdd(&cur[v & (PROWS - 1)], 1);
    t_csr[pos] = (int)(v >> PSHIFT);
  }
}

// ---------------------------------------------------------------------------
// One-shot W preparation for the MFMA intent role.
// Per W (user=seg0, item=seg1), seg layout in shorts:
//   [0,8192)      w1 B-frags hi: frag f=nt*2+ks, lane, e -> W[8*(l>>4)+e+32*ks][16*nt+(l&15)]
//   [8192,16384)  w1 B-frags lo
//   [16384,24576) W row-major bf16 hi  (B-frags of W^T read contiguously from here)
//   [24576,32768) W row-major bf16 lo
// ---------------------------------------------------------------------------
__global__ void k_wprep(const float* __restrict__ wu, const float* __restrict__ wi,
                        unsigned short* __restrict__ wbuf){
  const float* W = blockIdx.x ? wi : wu;
  unsigned short* seg = wbuf + blockIdx.x * 32768;
  int tid = threadIdx.x;
  for (int i = tid; i < DIM * N_INTENTS; i += 256){
    unsigned short h, l; split2(W[i], h, l);
    seg[16384 + i] = h; seg[24576 + i] = l;
  }
  for (int idx = tid; idx < 16 * 64; idx += 256){
    int f = idx >> 6, lane = idx & 63;
    int nt = f >> 1, ks = f & 1, g = lane >> 4, c = lane & 15;
    int in = 16 * nt + c;
#pragma unroll
    for (int e = 0; e < 8; e++){
      int d = 8 * g + e + 32 * ks;
      unsigned short h, l; split2(W[d * N_INTENTS + in], h, l);
      seg[f * 512 + lane * 8 + e] = h;
      seg[8192 + f * 512 + lane * 8 + e] = l;
    }
  }
}

// ---------------------------------------------------------------------------
// FUSED layer-front kernel: spmm_gnn + intent, heterogeneous block roles.
// Both roles read only layer-input emb/embb -> independent. 1-in-17 blocks
// run the VALU/MFMA-heavy intent (softmax(emb@W)@W^T); the rest run the
// gather-stall-heavy spmm. Intent compute fills spmm's memory-stall shadow.
// No __syncthreads anywhere; LDS slice is wave-private (intent role only).
// ---------------------------------------------------------------------------
__global__ __launch_bounds__(256) void k_gnn_intent(
    const int* __restrict__ rp, const int* __restrict__ t_csr,
    const float* __restrict__ dis, const unsigned short* __restrict__ embb,
    const float* __restrict__ emb, const unsigned short* __restrict__ wbuf,
    float* __restrict__ gnn, unsigned short* __restrict__ hgAB,
    unsigned short* __restrict__ out_bf){
  __shared__ __align__(16) unsigned int Pl[4][2048];   // 8KB/wave (intent role)
  int bid = blockIdx.x;
  int wid = threadIdx.x >> 6, lane = threadIdx.x & 63;

  if ((bid % 17) == 16){
    // ================= intent role =================
    int gt = (bid / 17) * 4 + wid;
    if (gt >= TOT_TILES) return;
    int node0; const unsigned short* wseg;
    if (gt < UT_TILES){ node0 = gt * 16;                       wseg = wbuf; }
    else              { node0 = N_USERS + (gt - UT_TILES) * 16; wseg = wbuf + 32768; }
    int g = lane >> 4, c = lane & 15;

    // ---- A-frags of E (hi/lo), node row = node0 + c, dims 8g..8g+7 (+32 for ks=1)
    const float4* erow = (const float4*)(emb + (size_t)(node0 + c) * DIM);
    float4 ea0 = erow[2 * g],     eb0 = erow[2 * g + 1];
    float4 ea1 = erow[8 + 2 * g], eb1 = erow[9 + 2 * g];
    short8v ehi[2], elo[2];
    {
      float xs[16] = {ea0.x, ea0.y, ea0.z, ea0.w, eb0.x, eb0.y, eb0.z, eb0.w,
                      ea1.x, ea1.y, ea1.z, ea1.w, eb1.x, eb1.y, eb1.z, eb1.w};
#pragma unroll
      for (int ksi = 0; ksi < 2; ksi++)
#pragma unroll
        for (int e = 0; e < 8; e++){
          unsigned short h, l; split2(xs[ksi * 8 + e], h, l);
          ehi[ksi][e] = (short)h; elo[ksi][e] = (short)l;
        }
    }

    // ---- matmul1: L = E @ W  (8 n-tiles of 16 intents, K=64 in 2 steps)
    const uint4* w1hi = (const uint4*)wseg;
    const uint4* w1lo = (const uint4*)(wseg + 8192);
    f32x4 acc1[8];
#pragma unroll
    for (int nt = 0; nt < 8; nt++){
      f32x4 a = {0.f, 0.f, 0.f, 0.f};
#pragma unroll
      for (int ks = 0; ks < 2; ks++){
        short8v wh = __builtin_bit_cast(short8v, w1hi[(nt * 2 + ks) * 64 + lane]);
        short8v wl = __builtin_bit_cast(short8v, w1lo[(nt * 2 + ks) * 64 + lane]);
        a = __builtin_amdgcn_mfma_f32_16x16x32_bf16(ehi[ks], wh, a, 0, 0, 0);
        a = __builtin_amdgcn_mfma_f32_16x16x32_bf16(elo[ks], wh, a, 0, 0, 0);
        a = __builtin_amdgcn_mfma_f32_16x16x32_bf16(ehi[ks], wl, a, 0, 0, 0);
      }
      acc1[nt] = a;
    }

    // ---- softmax per node (row r of D = node 4g+r). Normalized P packed hi|lo
    // into wave-private LDS, XOR-swizzled for conflict-free frag reads.
    unsigned int* pw = &Pl[wid][0];
#pragma unroll
    for (int r = 0; r < 4; r++){
      float m = acc1[0][r];
#pragma unroll
      for (int nt = 1; nt < 8; nt++) m = fmaxf(m, acc1[nt][r]);
      m = row16_allmax(m);
      float p[8];
      float s = 0.f;
#pragma unroll
      for (int nt = 0; nt < 8; nt++){ p[nt] = __expf(acc1[nt][r] - m); s += p[nt]; }
      s = row16_allsum(s);
      float inv = 1.f / s;
      int node = 4 * g + r;
      int swz = (node & 7) << 2;
      int base = node * 128 + c;
#pragma unroll
      for (int nt = 0; nt < 8; nt++){
        float v = p[nt] * inv;
        unsigned short h, l; split2(v, h, l);
        pw[(base + 16 * nt) ^ swz] = (unsigned int)h | ((unsigned int)l << 16);
      }
    }

    // ---- A-frags of P for matmul2: node = c, intents 8g..8g+7 (+32*ks)
    const uint4* pr = (const uint4*)pw;
    short8v phf[4], plf[4];
    int sw = (c & 7) << 2;
#pragma unroll
    for (int ks = 0; ks < 4; ks++){
      int i0 = c * 128 + 8 * g + 32 * ks;
      uint4 ra = pr[(i0 ^ sw) >> 2];
      uint4 rb = pr[((i0 + 4) ^ sw) >> 2];
      unsigned int q[8] = {ra.x, ra.y, ra.z, ra.w, rb.x, rb.y, rb.z, rb.w};
#pragma unroll
      for (int e = 0; e < 8; e++){
        phf[ks][e] = (short)(q[e] & 0xFFFFu);
        plf[ks][e] = (short)(q[e] >> 16);
      }
    }

    // ---- matmul2: O = P @ W^T. B-frags of W^T are contiguous rows of
    // row-major bf16 W: row = 16*nt + c, cols 8g..8g+7 (+32*ks).
    const uint4* w2hi = (const uint4*)(wseg + 16384);
    const uint4* w2lo = (const uint4*)(wseg + 24576);
    f32x4 acc2[4];
#pragma unroll
    for (int nt = 0; nt < 4; nt++){
      f32x4 a = {0.f, 0.f, 0.f, 0.f};
#pragma unroll
      for (int ks = 0; ks < 4; ks++){
        int fi = (16 * nt + c) * 16 + ks * 4 + g;
        short8v wh = __builtin_bit_cast(short8v, w2hi[fi]);
        short8v wl = __builtin_bit_cast(short8v, w2lo[fi]);
        a = __builtin_amdgcn_mfma_f32_16x16x32_bf16(phf[ks], wh, a, 0, 0, 0);
        a = __builtin_amdgcn_mfma_f32_16x16x32_bf16(plf[ks], wh, a, 0, 0, 0);
        a = __builtin_amdgcn_mfma_f32_16x16x32_bf16(phf[ks], wl, a, 0, 0, 0);
      }
      acc2[nt] = a;
    }

    // ---- outputs: D[m=4g+r][n=c] -> node 4g+r, dim 16*nt + c.
#pragma unroll
    for (int r = 0; r < 4; r++){
      float sq = 0.f;
#pragma unroll
      for (int nt = 0; nt < 4; nt++) sq = fmaf(acc2[nt][r], acc2[nt][r], sq);
      sq = row16_allsum(sq);
      float invn = 1.f / fmaxf(sqrtf(sq), 1e-8f);
      size_t node = (size_t)(node0 + 4 * g + r);
      unsigned short* hw = hgAB + node * 128 + 64;
      size_t obase = node * DIM + c;
#pragma unroll
      for (int nt = 0; nt < 4; nt++){
        float v = acc2[nt][r];
        out_bf[obase + 16 * nt] = f2bf(v);
        hw[16 * nt + c] = f2bf(v * invn);
      }
    }
  } else {
    // ================= spmm role =================
    int sidx = bid - bid / 17;          // dense index over spmm blocks
    int w = sidx * 4 + wid;
    if (w >= N_NODES) return;
    int slot = lane >> 3, sub = lane & 7;      // 8 slots x 8 dims
    int s = rp[w], e = rp[w + 1];
    float a0=0.f,a1=0.f,a2=0.f,a3=0.f,a4=0.f,a5=0.f,a6=0.f,a7=0.f;
    if (e > s){
      int i = s + slot;
      int t0 = t_csr[min(i, e - 1)];
      int t1 = t_csr[min(i + 8, e - 1)];
      float wt0 = dis[t0];
      uint4 ev0 = *(const uint4*)(embb + (size_t)t0 * 64 + 8 * sub);
      for (; i < e; i += 8){
        int t2 = t_csr[min(i + 16, e - 1)];
        float wt1 = dis[t1];
        uint4 ev1 = *(const uint4*)(embb + (size_t)t1 * 64 + 8 * sub);
        a0 = fmaf(wt0, bf_lo(ev0.x), a0); a1 = fmaf(wt0, bf_hi(ev0.x), a1);
        a2 = fmaf(wt0, bf_lo(ev0.y), a2); a3 = fmaf(wt0, bf_hi(ev0.y), a3);
        a4 = fmaf(wt0, bf_lo(ev0.z), a4); a5 = fmaf(wt0, bf_hi(ev0.z), a5);
        a6 = fmaf(wt0, bf_lo(ev0.w), a6); a7 = fmaf(wt0, bf_hi(ev0.w), a7);
        wt0 = wt1; ev0 = ev1; t1 = t2;
      }
    }
#pragma unroll
    for (int m = 8; m <= 32; m <<= 1){
      a0 += __shfl_xor(a0, m, 64); a1 += __shfl_xor(a1, m, 64);
      a2 += __shfl_xor(a2, m, 64); a3 += __shfl_xor(a3, m, 64);
      a4 += __shfl_xor(a4, m, 64); a5 += __shfl_xor(a5, m, 64);
      a6 += __shfl_xor(a6, m, 64); a7 += __shfl_xor(a7, m, 64);
    }
    float dw = dis[w];
    float g0 = dw*a0, g1 = dw*a1, g2 = dw*a2, g3 = dw*a3;
    float g4 = dw*a4, g5 = dw*a5, g6 = dw*a6, g7 = dw*a7;
    float sq = g0*g0 + g1*g1 + g2*g2 + g3*g3 + g4*g4 + g5*g5 + g6*g6 + g7*g7;
#pragma unroll
    for (int m = 1; m <= 4; m <<= 1) sq += __shfl_xor(sq, m, 64);
    float invn = 1.f / fmaxf(sqrtf(sq), 1e-8f);
    if (slot == 0){
      float4 v0 = make_float4(g0, g1, g2, g3);
      float4 v1 = make_float4(g4, g5, g6, g7);
      ((float4*)gnn)[w * 16 + 2 * sub]     = v0;
      ((float4*)gnn)[w * 16 + 2 * sub + 1] = v1;
      uint4 ob;
      ob.x = (unsigned)f2bf(g0*invn) | ((unsigned)f2bf(g1*invn) << 16);
      ob.y = (unsigned)f2bf(g2*invn) | ((unsigned)f2bf(g3*invn) << 16);
      ob.z = (unsigned)f2bf(g4*invn) | ((unsigned)f2bf(g5*invn) << 16);
      ob.w = (unsigned)f2bf(g6*invn) | ((unsigned)f2bf(g7*invn) << 16);
      *(uint4*)(hgAB + (size_t)w * 128 + 8 * sub) = ob;
    }
  }
}

// ---------------------------------------------------------------------------
// Fused adaptive passes + residual + acc + bf16 emb for next layer.
// Per 16-edge batch: gathered neighbor hgAB records form MFMA A-frags;
// B = broadcast hgAB[w]. SW-pipelined with PEELED last iteration: the
// prefetch is only issued when a real next batch exists (wave-uniform bound),
// eliminating the clamped-dup tail fetch (~384B/node of dead traffic).
// ---------------------------------------------------------------------------
__global__ void k_adafuse(const int* __restrict__ rp, const int* __restrict__ t_csr,
                          const unsigned short* __restrict__ hgAB,
                          const uint2* __restrict__ inte_bf2,
                          const unsigned short* __restrict__ embb,
                          const float* __restrict__ emb,
                          float* __restrict__ gnn_io, float* __restrict__ acc,
                          uint2* __restrict__ embb_next2){
  int w = (blockIdx.x * 256 + threadIdx.x) >> 6;
  int lane = threadIdx.x & 63;
  if (w >= N_NODES) return;
  int g = lane >> 4, c = lane & 15;
  // B-frags: hgAB[w] broadcast, hoisted
  const unsigned short* wr = hgAB + (size_t)w * 128;
  short8v bA0 = *(const short8v*)(wr + 8 * g);
  short8v bA1 = *(const short8v*)(wr + 8 * g + 32);
  short8v bB0 = *(const short8v*)(wr + 64 + 8 * g);
  short8v bB1 = *(const short8v*)(wr + 96 + 8 * g);
  int s = rp[w], e = rp[w + 1];
  float4 s1 = make_float4(0.f, 0.f, 0.f, 0.f);
  float4 s2 = make_float4(0.f, 0.f, 0.f, 0.f);
  float r1 = 0.f, r2 = 0.f;

  auto loadA = [&](int i, short8v& A0, short8v& A1, short8v& B0, short8v& B1){
    int ia = min(i + c, e - 1);
    int t = t_csr[ia];
    const unsigned short* ra = hgAB + (size_t)t * 128;
    A0 = *(const short8v*)(ra + 8 * g);
    A1 = *(const short8v*)(ra + 8 * g + 32);
    B0 = *(const short8v*)(ra + 64 + 8 * g);
    B1 = *(const short8v*)(ra + 96 + 8 * g);
  };
  auto loadE = [&](int i, uint2& E0, uint2& E1, uint2& E2, uint2& E3){
    int eb = i + 4 * g;
    E0 = *(const uint2*)(embb + (size_t)t_csr[min(eb,     e-1)] * 64 + 4 * c);
    E1 = *(const uint2*)(embb + (size_t)t_csr[min(eb + 1, e-1)] * 64 + 4 * c);
    E2 = *(const uint2*)(embb + (size_t)t_csr[min(eb + 2, e-1)] * 64 + 4 * c);
    E3 = *(const uint2*)(embb + (size_t)t_csr[min(eb + 3, e-1)] * 64 + 4 * c);
  };
  auto body = [&](int i, short8v aA0, short8v aA1, short8v aB0, short8v aB1,
                  uint2 ev0, uint2 ev1, uint2 ev2, uint2 ev3){
    f32x4 p = {0.f, 0.f, 0.f, 0.f};
    f32x4 q = {0.f, 0.f, 0.f, 0.f};
    p = __builtin_amdgcn_mfma_f32_16x16x32_bf16(aA0, bA0, p, 0, 0, 0);
    p = __builtin_amdgcn_mfma_f32_16x16x32_bf16(aA1, bA1, p, 0, 0, 0);
    q = __builtin_amdgcn_mfma_f32_16x16x32_bf16(aB0, bB0, q, 0, 0, 0);
    q = __builtin_amdgcn_mfma_f32_16x16x32_bf16(aB1, bB1, q, 0, 0, 0);
    int ebase = i + 4 * g;
    {
      bool valid = ebase < e;
      float a1v = valid ? fmaf(p[0], 0.5f, 0.5f) : 0.f;
      float a2v = valid ? fmaf(q[0], 0.5f, 0.5f) : 0.f;
      r1 += a1v; r2 += a2v;
      float v0 = bf_lo(ev0.x), v1 = bf_hi(ev0.x), v2 = bf_lo(ev0.y), v3 = bf_hi(ev0.y);
      s1.x = fmaf(a1v, v0, s1.x); s1.y = fmaf(a1v, v1, s1.y);
      s1.z = fmaf(a1v, v2, s1.z); s1.w = fmaf(a1v, v3, s1.w);
      s2.x = fmaf(a2v, v0, s2.x); s2.y = fmaf(a2v, v1, s2.y);
      s2.z = fmaf(a2v, v2, s2.z); s2.w = fmaf(a2v, v3, s2.w);
    }
    {
      bool valid = (ebase + 1) < e;
      float a1v = valid ? fmaf(p[1], 0.5f, 0.5f) : 0.f;
      float a2v = valid ? fmaf(q[1], 0.5f, 0.5f) : 0.f;
      r1 += a1v; r2 += a2v;
      float v0 = bf_lo(ev1.x), v1 = bf_hi(ev1.x), v2 = bf_lo(ev1.y), v3 = bf_hi(ev1.y);
      s1.x = fmaf(a1v, v0, s1.x); s1.y = fmaf(a1v, v1, s1.y);
      s1.z = fmaf(a1v, v2, s1.z); s1.w = fmaf(a1v, v3, s1.w);
      s2.x = fmaf(a2v, v0, s2.x); s2.y = fmaf(a2v, v1, s2.y);
      s2.z = fmaf(a2v, v2, s2.z); s2.w = fmaf(a2v, v3, s2.w);
    }
    {
      bool valid = (ebase + 2) < e;
      float a1v = valid ? fmaf(p[2], 0.5f, 0.5f) : 0.f;
      float a2v = valid ? fmaf(q[2], 0.5f, 0.5f) : 0.f;
      r1 += a1v; r2 += a2v;
      float v0 = bf_lo(ev2.x), v1 = bf_hi(ev2.x), v2 = bf_lo(ev2.y), v3 = bf_hi(ev2.y);
      s1.x = fmaf(a1v, v0, s1.x); s1.y = fmaf(a1v, v1, s1.y);
      s1.z = fmaf(a1v, v2, s1.z); s1.w = fmaf(a1v, v3, s1.w);
      s2.x = fmaf(a2v, v0, s2.x); s2.y = fmaf(a2v, v1, s2.y);
      s2.z = fmaf(a2v, v2, s2.z); s2.w = fmaf(a2v, v3, s2.w);
    }
    {
      bool valid = (ebase + 3) < e;
      float a1v = valid ? fmaf(p[3], 0.5f, 0.5f) : 0.f;
      float a2v = valid ? fmaf(q[3], 0.5f, 0.5f) : 0.f;
      r1 += a1v; r2 += a2v;
      float v0 = bf_lo(ev3.x), v1 = bf_hi(ev3.x), v2 = bf_lo(ev3.y), v3 = bf_hi(ev3.y);
      s1.x = fmaf(a1v, v0, s1.x); s1.y = fmaf(a1v, v1, s1.y);
      s1.z = fmaf(a1v, v2, s1.z); s1.w = fmaf(a1v, v3, s1.w);
      s2.x = fmaf(a2v, v0, s2.x); s2.y = fmaf(a2v, v1, s2.y);
      s2.z = fmaf(a2v, v2, s2.z); s2.w = fmaf(a2v, v3, s2.w);
    }
  };

  if (e > s){
    short8v aA0, aA1, aB0, aB1;
    uint2 ev0, ev1, ev2, ev3;
    loadA(s, aA0, aA1, aB0, aB1);
    loadE(s, ev0, ev1, ev2, ev3);
    int i = s;
    for (; i + 16 < e; i += 16){
      short8v nA0, nA1, nB0, nB1;
      uint2 ne0, ne1, ne2, ne3;
      loadA(i + 16, nA0, nA1, nB0, nB1);
      loadE(i + 16, ne0, ne1, ne2, ne3);
      body(i, aA0, aA1, aB0, aB1, ev0, ev1, ev2, ev3);
      aA0 = nA0; aA1 = nA1; aB0 = nB0; aB1 = nB1;
      ev0 = ne0; ev1 = ne1; ev2 = ne2; ev3 = ne3;
    }
    body(i, aA0, aA1, aB0, aB1, ev0, ev1, ev2, ev3);   // peeled last batch
  }
#pragma unroll
  for (int m = 16; m <= 32; m <<= 1){
    s1.x += __shfl_xor(s1.x, m, 64); s1.y += __shfl_xor(s1.y, m, 64);
    s1.z += __shfl_xor(s1.z, m, 64); s1.w += __shfl_xor(s1.w, m, 64);
    s2.x += __shfl_xor(s2.x, m, 64); s2.y += __shfl_xor(s2.y, m, 64);
    s2.z += __shfl_xor(s2.z, m, 64); s2.w += __shfl_xor(s2.w, m, 64);
    r1   += __shfl_xor(r1,   m, 64); r2   += __shfl_xor(r2,   m, 64);
  }
  float d1 = (r1 > 0.f) ? 1.f / r1 : 0.f;
  float d2 = (r2 > 0.f) ? 1.f / r2 : 0.f;
  if (g == 0){
    int idx4 = w * 16 + c;
    float4 gg = ((float4*)gnn_io)[idx4];
    uint2 it = inte_bf2[idx4];
    float4 em = ((const float4*)emb)[idx4];
    float4 nv;
    nv.x = gg.x + bf_lo(it.x) + em.x + d1 * s1.x + d2 * s2.x;
    nv.y = gg.y + bf_hi(it.x) + em.y + d1 * s1.y + d2 * s2.y;
    nv.z = gg.z + bf_lo(it.y) + em.z + d1 * s1.z + d2 * s2.z;
    nv.w = gg.w + bf_hi(it.y) + em.w + d1 * s1.w + d2 * s2.w;
    ((float4*)gnn_io)[idx4] = nv;
    float4 ac = ((float4*)acc)[idx4];
    ac.x += nv.x; ac.y += nv.y; ac.z += nv.z; ac.w += nv.w;
    ((float4*)acc)[idx4] = ac;
    uint2 ob;
    ob.x = (unsigned)f2bf(nv.x) | ((unsigned)f2bf(nv.y) << 16);
    ob.y = (unsigned)f2bf(nv.z) | ((unsigned)f2bf(nv.w) << 16);
    embb_next2[idx4] = ob;   // bf16 emb for next layer (other buffer: no race)
  }
}

extern "C" void kernel_launch(void* const* d_in, const int* in_sizes, int n_in,
                              void* d_out, int out_size, void* d_ws, size_t ws_size,
                              hipStream_t stream){
  const float* ue = (const float*)d_in[0];
  const float* ie = (const float*)d_in[1];
  const float* wu = (const float*)d_in[2];
  const float* wi = (const float*)d_in[3];
  const int* all_h = (const int*)d_in[4];
  const int* all_t = (const int*)d_in[5];
  float* acc = (float*)d_out;

  char* p = (char*)d_ws;
  auto take = [&](size_t bytes)->char*{
    char* r = p; p += (bytes + 255) & ~size_t(255); return r;
  };
  float*  embA  = (float*)take(sizeof(float) * N_NODES * DIM);
  float*  embB  = (float*)take(sizeof(float) * N_NODES * DIM);
  unsigned short* hgAB = (unsigned short*)take(sizeof(short) * N_NODES * 128);
  unsigned short* inte_bf = (unsigned short*)take(sizeof(short) * N_NODES * DIM);
  unsigned short* embbA   = (unsigned short*)take(sizeof(short) * N_NODES * DIM);
  unsigned short* embbB   = (unsigned short*)take(sizeof(short) * N_NODES * DIM);
  unsigned short* wbuf    = (unsigned short*)take(sizeof(short) * 2 * 32768);
  int*    t_csr = (int*)take(sizeof(int) * N_EDGES);
  float*  dis   = (float*)take(sizeof(float) * N_NODES);
  int*    deg   = (int*)take(sizeof(int) * N_NODES);
  int*    tmp   = (int*)take(sizeof(int) * N_NODES);
  int*    aux   = (int*)take(sizeof(int) * 1024);
  int*    rp    = (int*)take(sizeof(int) * (N_NODES + 1));
  int*    gcur  = (int*)take(sizeof(int) * NPART);
  if ((size_t)(p - (char*)d_ws) > ws_size) return;
  // staging (12 MB) aliases hgAB (38.4 MB): only live before spmm writes hgAB
  unsigned int* stg = (unsigned int*)hgAB;

  const int ELEM_B  = (N_NODES * DIM + 255) / 256;
  const int NODEW_B = (N_NODES * 64 + 255) / 256;
  const int EDGE_B  = (N_EDGES + 255) / 256;
  const int NODE_B  = (N_NODES + 255) / 256;

  hipMemsetAsync(deg, 0, sizeof(int) * N_NODES, stream);
  k_init<<<ELEM_B, 256, 0, stream>>>(ue, ie, embA, acc, embbA);
  k_wprep<<<2, 256, 0, stream>>>(wu, wi, wbuf);
  k_deg<<<EDGE_B, 256, 0, stream>>>(all_h, deg);
  k_scan1<<<NODE_B, 256, 0, stream>>>(deg, tmp, aux);
  k_scan2<<<1, 1024, 0, stream>>>(aux, NODE_B);
  k_rowptr<<<NODE_B, 256, 0, stream>>>(tmp, deg, aux, rp, dis, gcur);
  k_part1<<<NCHB, 256, 0, stream>>>(all_h, all_t, gcur, stg);
  k_part2<<<NPART, 256, 0, stream>>>(rp, stg, t_csr);

  float* eA = embA;
  float* eB = embB;
  unsigned short* ebA = embbA;  // bf16 of current emb
  unsigned short* ebB = embbB;
  for (int layer = 0; layer < 2; layer++){
    k_gnn_intent<<<FUSED_G, 256, 0, stream>>>(rp, t_csr, dis, ebA, eA, wbuf,
                                              eB, hgAB, inte_bf);
    k_adafuse<<<NODEW_B, 256, 0, stream>>>(rp, t_csr, hgAB,
                                           (const uint2*)inte_bf, ebA,
                                           eA, eB, acc, (uint2*)ebB);
    float* t = eA; eA = eB; eB = t;
    unsigned short* tb = ebA; ebA = ebB; ebB = tb;
  }
}

// Round 5
// 1008.303 us; speedup vs baseline: 1.0848x; 1.0848x over previous
//
#include <hip/hip_runtime.h>
#include <hip/hip_bf16.h>

#define N_USERS   50000
#define N_ITEMS   100000
#define N_NODES   150000
#define DIM       64
#define N_INTENTS 128
#define N_EDGES   3000000
#define PSHIFT    9                         // 512 rows per partition
#define PROWS     (1 << PSHIFT)
#define NPART     ((N_NODES + PROWS - 1) >> PSHIFT)   // 293
#define CHUNK     16384                     // edges per binning block
#define NCHB      ((N_EDGES + CHUNK - 1) / CHUNK)     // 184

typedef __attribute__((ext_vector_type(8))) short short8v;  // 8 bf16 (4 VGPRs)
typedef __attribute__((ext_vector_type(4))) float f32x4;

static __device__ __forceinline__ float wsum64(float v){
#pragma unroll
  for (int m = 32; m >= 1; m >>= 1) v += __shfl_xor(v, m, 64);
  return v;
}

// ---- DPP 16-lane row reduction (full-rate VALU)
template<int CTRL>
static __device__ __forceinline__ float dpp_ror_add(float x){
  int t = __builtin_amdgcn_update_dpp(0, __builtin_bit_cast(int, x),
                                      CTRL, 0xF, 0xF, true);
  return x + __builtin_bit_cast(float, t);
}
static __device__ __forceinline__ float row16_allsum(float x){
  x = dpp_ror_add<0x128>(x);  // row_ror:8
  x = dpp_ror_add<0x124>(x);  // row_ror:4
  x = dpp_ror_add<0x122>(x);  // row_ror:2
  x = dpp_ror_add<0x121>(x);  // row_ror:1
  return x;
}
template<int CTRL>
static __device__ __forceinline__ float dpp_ror_max(float x){
  int t = __builtin_amdgcn_update_dpp(0, __builtin_bit_cast(int, x),
                                      CTRL, 0xF, 0xF, true);
  return fmaxf(x, __builtin_bit_cast(float, t));
}
static __device__ __forceinline__ float row16_allmax(float x){
  x = dpp_ror_max<0x128>(x);
  x = dpp_ror_max<0x124>(x);
  x = dpp_ror_max<0x122>(x);
  x = dpp_ror_max<0x121>(x);
  return x;
}

// bf16 pack/unpack
static __device__ __forceinline__ unsigned short f2bf(float x){
  __hip_bfloat16 h = __float2bfloat16(x);
  return __builtin_bit_cast(unsigned short, h);
}
static __device__ __forceinline__ float bf_lo(unsigned int v){
  return __builtin_bit_cast(float, v << 16);
}
static __device__ __forceinline__ float bf_hi(unsigned int v){
  return __builtin_bit_cast(float, v & 0xFFFF0000u);
}
static __device__ __forceinline__ float bfval(unsigned short h){
  return __builtin_bit_cast(float, (unsigned int)h << 16);
}
// hi/lo bf16 split: x ~= bf(hi) + bf(lo), rel err ~2^-17 (fp32-fidelity for MFMA)
static __device__ __forceinline__ void split2(float x, unsigned short& hi,
                                              unsigned short& lo){
  hi = f2bf(x);
  lo = f2bf(x - bfval(hi));
}

// emb = concat(user_emb, item_emb); acc(=d_out) = emb; embb = bf16(emb)
__global__ void k_init(const float* __restrict__ ue, const float* __restrict__ ie,
                       float* __restrict__ emb, float* __restrict__ acc,
                       unsigned short* __restrict__ embb){
  int i = blockIdx.x * 256 + threadIdx.x;
  if (i >= N_NODES * DIM) return;
  float v = (i < N_USERS * DIM) ? ue[i] : ie[i - N_USERS * DIM];
  emb[i] = v; acc[i] = v; embb[i] = f2bf(v);
}

__global__ void k_deg(const int* __restrict__ h, int* __restrict__ deg){
  int e = blockIdx.x * 256 + threadIdx.x;
  if (e < N_EDGES) atomicAdd(&deg[h[e]], 1);
}

__global__ void k_scan1(const int* __restrict__ deg, int* __restrict__ tmp,
                        int* __restrict__ aux){
  __shared__ int s[256];
  int t = threadIdx.x, i = blockIdx.x * 256 + t;
  int v = (i < N_NODES) ? deg[i] : 0;
  s[t] = v; __syncthreads();
  for (int off = 1; off < 256; off <<= 1){
    int x = (t >= off) ? s[t - off] : 0;
    __syncthreads();
    s[t] += x;
    __syncthreads();
  }
  if (i < N_NODES) tmp[i] = s[t];
  if (t == 255) aux[blockIdx.x] = s[255];
}

__global__ __launch_bounds__(1024) void k_scan2(int* __restrict__ aux, int n){
  __shared__ int s[1024];
  int t = threadIdx.x;
  int v = (t < n) ? aux[t] : 0;
  s[t] = v; __syncthreads();
  for (int off = 1; off < 1024; off <<= 1){
    int x = (t >= off) ? s[t - off] : 0;
    __syncthreads();
    s[t] += x;
    __syncthreads();
  }
  if (t < n) aux[t] = s[t] - v;   // exclusive
}

__global__ void k_rowptr(const int* __restrict__ tmp, const int* __restrict__ deg,
                         const int* __restrict__ aux, int* __restrict__ rp,
                         float* __restrict__ dis, int* __restrict__ gcur){
  int i = blockIdx.x * 256 + threadIdx.x;
  if (i < N_NODES){
    int v = aux[i >> 8] + tmp[i] - deg[i];
    rp[i] = v;
    int d = deg[i];
    dis[i] = (d > 0) ? (1.f / sqrtf((float)d)) : 0.f;
    if ((i & (PROWS - 1)) == 0) gcur[i >> PSHIFT] = v;  // partition append cursor
  }
  if (i == 0) rp[N_NODES] = N_EDGES;
}

// Counting-sort pass 1: per-block LDS histogram over 293 partitions, ONE
// global reservation per (block,partition), then scatter into block-exclusive
// contiguous runs.
__global__ __launch_bounds__(256) void k_part1(const int* __restrict__ h,
                                               const int* __restrict__ t,
                                               int* __restrict__ gcur,
                                               unsigned int* __restrict__ stg){
  __shared__ int hist[NPART];
  __shared__ int base[NPART];
  __shared__ int cnt2[NPART];
  int tid = threadIdx.x;
  int s = blockIdx.x * CHUNK;
  int e = min(s + CHUNK, N_EDGES);
  for (int p = tid; p < NPART; p += 256){ hist[p] = 0; cnt2[p] = 0; }
  __syncthreads();
  for (int i = s + tid; i < e; i += 256)
    atomicAdd(&hist[h[i] >> PSHIFT], 1);
  __syncthreads();
  for (int p = tid; p < NPART; p += 256){
    int c = hist[p];
    base[p] = c ? atomicAdd(&gcur[p], c) : 0;
  }
  __syncthreads();
  for (int i = s + tid; i < e; i += 256){
    int hh = h[i];
    int part = hh >> PSHIFT;
    int pos = base[part] + atomicAdd(&cnt2[part], 1);
    stg[pos] = ((unsigned)t[i] << PSHIFT) | (unsigned)(hh & (PROWS - 1));
  }
}

// Counting-sort pass 2: one block per partition.
__global__ __launch_bounds__(256) void k_part2(const int* __restrict__ rp,
                                               const unsigned int* __restrict__ stg,
                                               int* __restrict__ t_csr){
  __shared__ int cur[PROWS];
  int b = blockIdx.x, tid = threadIdx.x;
  int row0 = b << PSHIFT;
  int rows = min(PROWS, N_NODES - row0);
  for (int i = tid; i < rows; i += 256) cur[i] = rp[row0 + i];
  __syncthreads();
  int s = rp[row0], e = rp[row0 + rows];
  for (int i = s + tid; i < e; i += 256){
    unsigned int v = stg[i];
    int pos = atomicAdd(&cur[v & (PROWS - 1)], 1);
    t_csr[pos] = (int)(v >> PSHIFT);
  }
}

// gnn[n] = dis[n] * sum_e dis[t_e] * emb[t_e]. 8 edges in flight per wave,
// 16B bf16 loads; L2-normalized row -> CONTIGUOUS lower half of hgAB record.
__global__ void k_spmm_gnn(const int* __restrict__ rp, const int* __restrict__ t_csr,
                           const float* __restrict__ dis,
                           const unsigned short* __restrict__ embb,
                           float* __restrict__ gnn, unsigned short* __restrict__ hgAB){
  int w = (blockIdx.x * 256 + threadIdx.x) >> 6;
  int lane = threadIdx.x & 63;
  if (w >= N_NODES) return;
  int slot = lane >> 3, sub = lane & 7;      // 8 slots x 8 dims
  int s = rp[w], e = rp[w + 1];
  float a0=0.f,a1=0.f,a2=0.f,a3=0.f,a4=0.f,a5=0.f,a6=0.f,a7=0.f;
  for (int i = s + slot; i < e; i += 8){
    int t = t_csr[i];
    float wt = dis[t];
    uint4 ev = *(const uint4*)(embb + (size_t)t * 64 + 8 * sub);
    a0 = fmaf(wt, bf_lo(ev.x), a0); a1 = fmaf(wt, bf_hi(ev.x), a1);
    a2 = fmaf(wt, bf_lo(ev.y), a2); a3 = fmaf(wt, bf_hi(ev.y), a3);
    a4 = fmaf(wt, bf_lo(ev.z), a4); a5 = fmaf(wt, bf_hi(ev.z), a5);
    a6 = fmaf(wt, bf_lo(ev.w), a6); a7 = fmaf(wt, bf_hi(ev.w), a7);
  }
#pragma unroll
  for (int m = 8; m <= 32; m <<= 1){
    a0 += __shfl_xor(a0, m, 64); a1 += __shfl_xor(a1, m, 64);
    a2 += __shfl_xor(a2, m, 64); a3 += __shfl_xor(a3, m, 64);
    a4 += __shfl_xor(a4, m, 64); a5 += __shfl_xor(a5, m, 64);
    a6 += __shfl_xor(a6, m, 64); a7 += __shfl_xor(a7, m, 64);
  }
  float dw = dis[w];
  float g0 = dw*a0, g1 = dw*a1, g2 = dw*a2, g3 = dw*a3;
  float g4 = dw*a4, g5 = dw*a5, g6 = dw*a6, g7 = dw*a7;
  float sq = g0*g0 + g1*g1 + g2*g2 + g3*g3 + g4*g4 + g5*g5 + g6*g6 + g7*g7;
#pragma unroll
  for (int m = 1; m <= 4; m <<= 1) sq += __shfl_xor(sq, m, 64);
  float invn = 1.f / fmaxf(sqrtf(sq), 1e-8f);
  if (slot == 0){
    float4 v0 = make_float4(g0, g1, g2, g3);
    float4 v1 = make_float4(g4, g5, g6, g7);
    ((float4*)gnn)[w * 16 + 2 * sub]     = v0;
    ((float4*)gnn)[w * 16 + 2 * sub + 1] = v1;
    uint4 ob;
    ob.x = (unsigned)f2bf(g0*invn) | ((unsigned)f2bf(g1*invn) << 16);
    ob.y = (unsigned)f2bf(g2*invn) | ((unsigned)f2bf(g3*invn) << 16);
    ob.z = (unsigned)f2bf(g4*invn) | ((unsigned)f2bf(g5*invn) << 16);
    ob.w = (unsigned)f2bf(g6*invn) | ((unsigned)f2bf(g7*invn) << 16);
    *(uint4*)(hgAB + (size_t)w * 128 + 8 * sub) = ob;   // lower half: hgA
  }
}

// ---------------------------------------------------------------------------
// One-shot W preparation for the MFMA intent kernel.
// Per W (user=seg0, item=seg1), seg layout in shorts:
//   [0,8192)      w1 B-frags hi: frag f=nt*2+ks, lane, e -> W[8*(l>>4)+e+32*ks][16*nt+(l&15)]
//   [8192,16384)  w1 B-frags lo
//   [16384,24576) W row-major bf16 hi  (B-frags of W^T read contiguously from here)
//   [24576,32768) W row-major bf16 lo
// ---------------------------------------------------------------------------
__global__ void k_wprep(const float* __restrict__ wu, const float* __restrict__ wi,
                        unsigned short* __restrict__ wbuf){
  const float* W = blockIdx.x ? wi : wu;
  unsigned short* seg = wbuf + blockIdx.x * 32768;
  int tid = threadIdx.x;
  for (int i = tid; i < DIM * N_INTENTS; i += 256){
    unsigned short h, l; split2(W[i], h, l);
    seg[16384 + i] = h; seg[24576 + i] = l;
  }
  for (int idx = tid; idx < 16 * 64; idx += 256){
    int f = idx >> 6, lane = idx & 63;
    int nt = f >> 1, ks = f & 1, g = lane >> 4, c = lane & 15;
    int in = 16 * nt + c;
#pragma unroll
    for (int e = 0; e < 8; e++){
      int d = 8 * g + e + 32 * ks;
      unsigned short h, l; split2(W[d * N_INTENTS + in], h, l);
      seg[f * 512 + lane * 8 + e] = h;
      seg[8192 + f * 512 + lane * 8 + e] = l;
    }
  }
}

// ---------------------------------------------------------------------------
// MFMA intent kernel: out = softmax(emb @ W) @ W^T, bf16 out + L2-norm into
// the UPPER half of the hgAB record. One 16-node tile per wave; no barriers.
// mfma_f32_16x16x32_bf16 layouts: A[m=l&15][k=8*(l>>4)+e],
// B[k=8*(l>>4)+e][n=l&15], D[m=4*(l>>4)+r][n=l&15].
// ---------------------------------------------------------------------------
__global__ __launch_bounds__(256) void k_intent_mfma(
    const unsigned short* __restrict__ wseg, const float* __restrict__ emb,
    unsigned short* __restrict__ out_bf, unsigned short* __restrict__ hgAB,
    int base_node, int count){
  __shared__ __align__(16) unsigned int Pl[4][2048];   // 8KB per wave: P hi|lo packed
  int wid = threadIdx.x >> 6, lane = threadIdx.x & 63;
  int tile = blockIdx.x * 4 + wid;
  if (tile * 16 >= count) return;
  int g = lane >> 4, c = lane & 15;

  // ---- A-frags of E (hi/lo), node row = tile*16 + c, dims 8g..8g+7 (+32 for ks=1)
  const float4* erow = (const float4*)(emb + (size_t)(base_node + tile * 16 + c) * DIM);
  float4 ea0 = erow[2 * g],     eb0 = erow[2 * g + 1];
  float4 ea1 = erow[8 + 2 * g], eb1 = erow[9 + 2 * g];
  short8v ehi[2], elo[2];
  {
    float xs[16] = {ea0.x, ea0.y, ea0.z, ea0.w, eb0.x, eb0.y, eb0.z, eb0.w,
                    ea1.x, ea1.y, ea1.z, ea1.w, eb1.x, eb1.y, eb1.z, eb1.w};
#pragma unroll
    for (int ksi = 0; ksi < 2; ksi++)
#pragma unroll
      for (int e = 0; e < 8; e++){
        unsigned short h, l; split2(xs[ksi * 8 + e], h, l);
        ehi[ksi][e] = (short)h; elo[ksi][e] = (short)l;
      }
  }

  // ---- matmul1: L = E @ W  (8 n-tiles of 16 intents, K=64 in 2 steps)
  const uint4* w1hi = (const uint4*)wseg;
  const uint4* w1lo = (const uint4*)(wseg + 8192);
  f32x4 acc1[8];
#pragma unroll
  for (int nt = 0; nt < 8; nt++){
    f32x4 a = {0.f, 0.f, 0.f, 0.f};
#pragma unroll
    for (int ks = 0; ks < 2; ks++){
      short8v wh = __builtin_bit_cast(short8v, w1hi[(nt * 2 + ks) * 64 + lane]);
      short8v wl = __builtin_bit_cast(short8v, w1lo[(nt * 2 + ks) * 64 + lane]);
      a = __builtin_amdgcn_mfma_f32_16x16x32_bf16(ehi[ks], wh, a, 0, 0, 0);
      a = __builtin_amdgcn_mfma_f32_16x16x32_bf16(elo[ks], wh, a, 0, 0, 0);
      a = __builtin_amdgcn_mfma_f32_16x16x32_bf16(ehi[ks], wl, a, 0, 0, 0);
    }
    acc1[nt] = a;
  }

  // ---- softmax per node (row r of D = node 4g+r). Normalized P packed hi|lo
  // into wave-private LDS, XOR-swizzled for conflict-free frag reads.
  unsigned int* pw = &Pl[wid][0];
#pragma unroll
  for (int r = 0; r < 4; r++){
    float m = acc1[0][r];
#pragma unroll
    for (int nt = 1; nt < 8; nt++) m = fmaxf(m, acc1[nt][r]);
    m = row16_allmax(m);
    float p[8];
    float s = 0.f;
#pragma unroll
    for (int nt = 0; nt < 8; nt++){ p[nt] = __expf(acc1[nt][r] - m); s += p[nt]; }
    s = row16_allsum(s);
    float inv = 1.f / s;
    int node = 4 * g + r;
    int swz = (node & 7) << 2;
    int base = node * 128 + c;
#pragma unroll
    for (int nt = 0; nt < 8; nt++){
      float v = p[nt] * inv;
      unsigned short h, l; split2(v, h, l);
      pw[(base + 16 * nt) ^ swz] = (unsigned int)h | ((unsigned int)l << 16);
    }
  }

  // ---- A-frags of P for matmul2: node = c, intents 8g..8g+7 (+32*ks)
  const uint4* pr = (const uint4*)pw;
  short8v phf[4], plf[4];
  int sw = (c & 7) << 2;
#pragma unroll
  for (int ks = 0; ks < 4; ks++){
    int i0 = c * 128 + 8 * g + 32 * ks;
    uint4 ra = pr[(i0 ^ sw) >> 2];
    uint4 rb = pr[((i0 + 4) ^ sw) >> 2];
    unsigned int q[8] = {ra.x, ra.y, ra.z, ra.w, rb.x, rb.y, rb.z, rb.w};
#pragma unroll
    for (int e = 0; e < 8; e++){
      phf[ks][e] = (short)(q[e] & 0xFFFFu);
      plf[ks][e] = (short)(q[e] >> 16);
    }
  }

  // ---- matmul2: O = P @ W^T. B-frags of W^T are contiguous rows of
  // row-major bf16 W: row = 16*nt + c, cols 8g..8g+7 (+32*ks).
  const uint4* w2hi = (const uint4*)(wseg + 16384);
  const uint4* w2lo = (const uint4*)(wseg + 24576);
  f32x4 acc2[4];
#pragma unroll
  for (int nt = 0; nt < 4; nt++){
    f32x4 a = {0.f, 0.f, 0.f, 0.f};
#pragma unroll
    for (int ks = 0; ks < 4; ks++){
      int fi = (16 * nt + c) * 16 + ks * 4 + g;
      short8v wh = __builtin_bit_cast(short8v, w2hi[fi]);
      short8v wl = __builtin_bit_cast(short8v, w2lo[fi]);
      a = __builtin_amdgcn_mfma_f32_16x16x32_bf16(phf[ks], wh, a, 0, 0, 0);
      a = __builtin_amdgcn_mfma_f32_16x16x32_bf16(plf[ks], wh, a, 0, 0, 0);
      a = __builtin_amdgcn_mfma_f32_16x16x32_bf16(phf[ks], wl, a, 0, 0, 0);
    }
    acc2[nt] = a;
  }

  // ---- outputs: D[m=4g+r][n=c] -> node 4g+r, dim 16*nt + c.
#pragma unroll
  for (int r = 0; r < 4; r++){
    float sq = 0.f;
#pragma unroll
    for (int nt = 0; nt < 4; nt++) sq = fmaf(acc2[nt][r], acc2[nt][r], sq);
    sq = row16_allsum(sq);
    float invn = 1.f / fmaxf(sqrtf(sq), 1e-8f);
    size_t node = (size_t)(base_node + tile * 16 + 4 * g + r);
    unsigned short* hw = hgAB + node * 128 + 64;   // upper half: hgB
    size_t obase = node * DIM + c;
#pragma unroll
    for (int nt = 0; nt < 4; nt++){
      float v = acc2[nt][r];
      out_bf[obase + 16 * nt] = f2bf(v);
      hw[16 * nt + c] = f2bf(v * invn);
    }
  }
}

// ---------------------------------------------------------------------------
// Fused adaptive passes + residual + acc + bf16 emb for next layer.
// R0-style occupancy-first structure: VALU dots, 4 edge slots/wave, ONE
// gathered uint4 per lane per edge (subs 0-7 = hgA dims, 8-15 = hgB dims of
// the interleaved 256B hgAB record), two masked row16 DPP reduces for the
// two cosines. No pipeline, no MFMA, no LDS -> minimal VGPR, max waves/CU.
// ---------------------------------------------------------------------------
__global__ void k_adafuse(const int* __restrict__ rp, const int* __restrict__ t_csr,
                          const uint4* __restrict__ hgAB4,
                          const uint2* __restrict__ inte_bf2,
                          const uint2* __restrict__ embb2,
                          const float* __restrict__ emb,
                          float* __restrict__ gnn_io, float* __restrict__ acc,
                          uint2* __restrict__ embb_next2){
  int w = (blockIdx.x * 256 + threadIdx.x) >> 6;
  int lane = threadIdx.x & 63;
  if (w >= N_NODES) return;
  int slot = lane >> 4, sub = lane & 15;
  // own record: lane holds 8 dims of hgA (sub<8) or hgB (sub>=8)
  uint4 hp = hgAB4[(size_t)w * 16 + sub];
  float w0 = bf_lo(hp.x), w1 = bf_hi(hp.x), w2 = bf_lo(hp.y), w3 = bf_hi(hp.y);
  float w4 = bf_lo(hp.z), w5 = bf_hi(hp.z), w6 = bf_lo(hp.w), w7 = bf_hi(hp.w);
  bool isA = sub < 8;
  int s = rp[w], e = rp[w + 1];
  float4 s1 = make_float4(0.f, 0.f, 0.f, 0.f);
  float4 s2 = make_float4(0.f, 0.f, 0.f, 0.f);
  float r1 = 0.f, r2 = 0.f;
  for (int i = s + slot; i < e; i += 4){
    int t = t_csr[i];
    uint4 tp = hgAB4[(size_t)t * 16 + sub];
    float part = w0 * bf_lo(tp.x) + w1 * bf_hi(tp.x)
               + w2 * bf_lo(tp.y) + w3 * bf_hi(tp.y)
               + w4 * bf_lo(tp.z) + w5 * bf_hi(tp.z)
               + w6 * bf_lo(tp.w) + w7 * bf_hi(tp.w);
    float p = row16_allsum(isA ? part : 0.f);
    float q = row16_allsum(isA ? 0.f : part);
    float a1 = fmaf(p, 0.5f, 0.5f);
    float a2 = fmaf(q, 0.5f, 0.5f);
    r1 += a1; r2 += a2;
    uint2 ev = embb2[(size_t)t * 16 + sub];
    float v0 = bf_lo(ev.x), v1 = bf_hi(ev.x), v2 = bf_lo(ev.y), v3 = bf_hi(ev.y);
    s1.x = fmaf(a1, v0, s1.x); s1.y = fmaf(a1, v1, s1.y);
    s1.z = fmaf(a1, v2, s1.z); s1.w = fmaf(a1, v3, s1.w);
    s2.x = fmaf(a2, v0, s2.x); s2.y = fmaf(a2, v1, s2.y);
    s2.z = fmaf(a2, v2, s2.z); s2.w = fmaf(a2, v3, s2.w);
  }
#pragma unroll
  for (int m = 16; m <= 32; m <<= 1){
    s1.x += __shfl_xor(s1.x, m, 64); s1.y += __shfl_xor(s1.y, m, 64);
    s1.z += __shfl_xor(s1.z, m, 64); s1.w += __shfl_xor(s1.w, m, 64);
    s2.x += __shfl_xor(s2.x, m, 64); s2.y += __shfl_xor(s2.y, m, 64);
    s2.z += __shfl_xor(s2.z, m, 64); s2.w += __shfl_xor(s2.w, m, 64);
    r1   += __shfl_xor(r1,   m, 64); r2   += __shfl_xor(r2,   m, 64);
  }
  float d1 = (r1 > 0.f) ? 1.f / r1 : 0.f;
  float d2 = (r2 > 0.f) ? 1.f / r2 : 0.f;
  if (slot == 0){
    int idx4 = w * 16 + sub;
    float4 gg = ((float4*)gnn_io)[idx4];
    uint2 it = inte_bf2[idx4];
    float4 em = ((const float4*)emb)[idx4];
    float4 nv;
    nv.x = gg.x + bf_lo(it.x) + em.x + d1 * s1.x + d2 * s2.x;
    nv.y = gg.y + bf_hi(it.x) + em.y + d1 * s1.y + d2 * s2.y;
    nv.z = gg.z + bf_lo(it.y) + em.z + d1 * s1.z + d2 * s2.z;
    nv.w = gg.w + bf_hi(it.y) + em.w + d1 * s1.w + d2 * s2.w;
    ((float4*)gnn_io)[idx4] = nv;
    float4 ac = ((float4*)acc)[idx4];
    ac.x += nv.x; ac.y += nv.y; ac.z += nv.z; ac.w += nv.w;
    ((float4*)acc)[idx4] = ac;
    uint2 ob;
    ob.x = (unsigned)f2bf(nv.x) | ((unsigned)f2bf(nv.y) << 16);
    ob.y = (unsigned)f2bf(nv.z) | ((unsigned)f2bf(nv.w) << 16);
    embb_next2[idx4] = ob;   // bf16 emb for next layer (other buffer: no race)
  }
}

extern "C" void kernel_launch(void* const* d_in, const int* in_sizes, int n_in,
                              void* d_out, int out_size, void* d_ws, size_t ws_size,
                              hipStream_t stream){
  const float* ue = (const float*)d_in[0];
  const float* ie = (const float*)d_in[1];
  const float* wu = (const float*)d_in[2];
  const float* wi = (const float*)d_in[3];
  const int* all_h = (const int*)d_in[4];
  const int* all_t = (const int*)d_in[5];
  float* acc = (float*)d_out;

  char* p = (char*)d_ws;
  auto take = [&](size_t bytes)->char*{
    char* r = p; p += (bytes + 255) & ~size_t(255); return r;
  };
  float*  embA  = (float*)take(sizeof(float) * N_NODES * DIM);
  float*  embB  = (float*)take(sizeof(float) * N_NODES * DIM);
  unsigned short* hgAB = (unsigned short*)take(sizeof(short) * N_NODES * 128);
  unsigned short* inte_bf = (unsigned short*)take(sizeof(short) * N_NODES * DIM);
  unsigned short* embbA   = (unsigned short*)take(sizeof(short) * N_NODES * DIM);
  unsigned short* embbB   = (unsigned short*)take(sizeof(short) * N_NODES * DIM);
  unsigned short* wbuf    = (unsigned short*)take(sizeof(short) * 2 * 32768);
  int*    t_csr = (int*)take(sizeof(int) * N_EDGES);
  float*  dis   = (float*)take(sizeof(float) * N_NODES);
  int*    deg   = (int*)take(sizeof(int) * N_NODES);
  int*    tmp   = (int*)take(sizeof(int) * N_NODES);
  int*    aux   = (int*)take(sizeof(int) * 1024);
  int*    rp    = (int*)take(sizeof(int) * (N_NODES + 1));
  int*    gcur  = (int*)take(sizeof(int) * NPART);
  if ((size_t)(p - (char*)d_ws) > ws_size) return;
  // staging (12 MB) aliases hgAB (38.4 MB): only live before spmm writes hgAB
  unsigned int* stg = (unsigned int*)hgAB;

  const int ELEM_B  = (N_NODES * DIM + 255) / 256;
  const int NODEW_B = (N_NODES * 64 + 255) / 256;
  const int EDGE_B  = (N_EDGES + 255) / 256;
  const int NODE_B  = (N_NODES + 255) / 256;

  hipMemsetAsync(deg, 0, sizeof(int) * N_NODES, stream);
  k_init<<<ELEM_B, 256, 0, stream>>>(ue, ie, embA, acc, embbA);
  k_wprep<<<2, 256, 0, stream>>>(wu, wi, wbuf);
  k_deg<<<EDGE_B, 256, 0, stream>>>(all_h, deg);
  k_scan1<<<NODE_B, 256, 0, stream>>>(deg, tmp, aux);
  k_scan2<<<1, 1024, 0, stream>>>(aux, NODE_B);
  k_rowptr<<<NODE_B, 256, 0, stream>>>(tmp, deg, aux, rp, dis, gcur);
  k_part1<<<NCHB, 256, 0, stream>>>(all_h, all_t, gcur, stg);
  k_part2<<<NPART, 256, 0, stream>>>(rp, stg, t_csr);

  const int UT_B = ((N_USERS / 16) + 3) / 4;   // user tiles -> blocks
  const int IT_B = ((N_ITEMS / 16) + 3) / 4;   // item tiles -> blocks

  float* eA = embA;
  float* eB = embB;
  unsigned short* ebA = embbA;  // bf16 of current emb
  unsigned short* ebB = embbB;
  for (int layer = 0; layer < 2; layer++){
    k_spmm_gnn<<<NODEW_B, 256, 0, stream>>>(rp, t_csr, dis, ebA, eB, hgAB);
    k_intent_mfma<<<UT_B, 256, 0, stream>>>(wbuf, eA, inte_bf, hgAB, 0, N_USERS);
    k_intent_mfma<<<IT_B, 256, 0, stream>>>(wbuf + 32768, eA, inte_bf, hgAB,
                                            N_USERS, N_ITEMS);
    k_adafuse<<<NODEW_B, 256, 0, stream>>>(rp, t_csr, (const uint4*)hgAB,
                                           (const uint2*)inte_bf,
                                           (const uint2*)ebA,
                                           eA, eB, acc, (uint2*)ebB);
    float* t = eA; eA = eB; eB = t;
    unsigned short* tb = ebA; ebA = ebB; ebB = tb;
  }
}

// Round 6
// 948.857 us; speedup vs baseline: 1.1528x; 1.0627x over previous
//
#include <hip/hip_runtime.h>
#include <hip/hip_bf16.h>

#define N_USERS   50000
#define N_ITEMS   100000
#define N_NODES   150000
#define DIM       64
#define N_INTENTS 128
#define N_EDGES   3000000
#define PSHIFT    9                         // 512 rows per partition
#define PROWS     (1 << PSHIFT)
#define NPART     ((N_NODES + PROWS - 1) >> PSHIFT)   // 293
#define CHUNK     16384                     // edges per binning block
#define NCHB      ((N_EDGES + CHUNK - 1) / CHUNK)     // 184

typedef __attribute__((ext_vector_type(8))) short short8v;  // 8 bf16 (4 VGPRs)
typedef __attribute__((ext_vector_type(4))) float f32x4;
typedef __attribute__((ext_vector_type(2))) float f32x2;

// ---- DPP 16-lane row reduction (full-rate VALU)
template<int CTRL>
static __device__ __forceinline__ float dpp_ror_add(float x){
  int t = __builtin_amdgcn_update_dpp(0, __builtin_bit_cast(int, x),
                                      CTRL, 0xF, 0xF, true);
  return x + __builtin_bit_cast(float, t);
}
static __device__ __forceinline__ float row16_allsum(float x){
  x = dpp_ror_add<0x128>(x);  // row_ror:8
  x = dpp_ror_add<0x124>(x);  // row_ror:4
  x = dpp_ror_add<0x122>(x);  // row_ror:2
  x = dpp_ror_add<0x121>(x);  // row_ror:1
  return x;
}
template<int CTRL>
static __device__ __forceinline__ float dpp_ror_max(float x){
  int t = __builtin_amdgcn_update_dpp(0, __builtin_bit_cast(int, x),
                                      CTRL, 0xF, 0xF, true);
  return fmaxf(x, __builtin_bit_cast(float, t));
}
static __device__ __forceinline__ float row16_allmax(float x){
  x = dpp_ror_max<0x128>(x);
  x = dpp_ror_max<0x124>(x);
  x = dpp_ror_max<0x122>(x);
  x = dpp_ror_max<0x121>(x);
  return x;
}

// bf16 pack/unpack
static __device__ __forceinline__ unsigned short f2bf(float x){
  __hip_bfloat16 h = __float2bfloat16(x);
  return __builtin_bit_cast(unsigned short, h);
}
static __device__ __forceinline__ float bf_lo(unsigned int v){
  return __builtin_bit_cast(float, v << 16);
}
static __device__ __forceinline__ float bf_hi(unsigned int v){
  return __builtin_bit_cast(float, v & 0xFFFF0000u);
}
static __device__ __forceinline__ float bfval(unsigned short h){
  return __builtin_bit_cast(float, (unsigned int)h << 16);
}
// hi/lo bf16 split: x ~= bf(hi) + bf(lo), rel err ~2^-17 (fp32-fidelity for MFMA)
static __device__ __forceinline__ void split2(float x, unsigned short& hi,
                                              unsigned short& lo){
  hi = f2bf(x);
  lo = f2bf(x - bfval(hi));
}

// ---- fp8 (OCP e4m3) HW converts. Decode: 8 fp8 -> 8 f32 in 4 instrs.
static __device__ __forceinline__ void fp8dec8(uint2 v, float* f){
  f32x2 a = __builtin_amdgcn_cvt_pk_f32_fp8(v.x, false);
  f32x2 b = __builtin_amdgcn_cvt_pk_f32_fp8(v.x, true);
  f32x2 c = __builtin_amdgcn_cvt_pk_f32_fp8(v.y, false);
  f32x2 d = __builtin_amdgcn_cvt_pk_f32_fp8(v.y, true);
  f[0]=a[0]; f[1]=a[1]; f[2]=b[0]; f[3]=b[1];
  f[4]=c[0]; f[5]=c[1]; f[6]=d[0]; f[7]=d[1];
}
static __device__ __forceinline__ unsigned char f2fp8(float x){
  return (unsigned char)(__builtin_amdgcn_cvt_pk_fp8_f32(x, x, 0, false) & 0xFF);
}

// emb = concat(user_emb, item_emb); acc(=d_out) = emb; embb = bf16(emb)
__global__ void k_init(const float* __restrict__ ue, const float* __restrict__ ie,
                       float* __restrict__ emb, float* __restrict__ acc,
                       unsigned short* __restrict__ embb){
  int i = blockIdx.x * 256 + threadIdx.x;
  if (i >= N_NODES * DIM) return;
  float v = (i < N_USERS * DIM) ? ue[i] : ie[i - N_USERS * DIM];
  emb[i] = v; acc[i] = v; embb[i] = f2bf(v);
}

// embd[n][d] = bf16(dis[n] * emb[n][d])  (layer-0 premultiplied gather array)
__global__ void k_embd0(const float* __restrict__ emb, const float* __restrict__ dis,
                        uint2* __restrict__ embd2){
  int i = blockIdx.x * 256 + threadIdx.x;     // over N_NODES*16 float4 groups
  if (i >= N_NODES * 16) return;
  float d = dis[i >> 4];
  float4 v = ((const float4*)emb)[i];
  uint2 ob;
  ob.x = (unsigned)f2bf(d * v.x) | ((unsigned)f2bf(d * v.y) << 16);
  ob.y = (unsigned)f2bf(d * v.z) | ((unsigned)f2bf(d * v.w) << 16);
  embd2[i] = ob;
}

__global__ void k_deg(const int* __restrict__ h, int* __restrict__ deg){
  int e = blockIdx.x * 256 + threadIdx.x;
  if (e < N_EDGES) atomicAdd(&deg[h[e]], 1);
}

__global__ void k_scan1(const int* __restrict__ deg, int* __restrict__ tmp,
                        int* __restrict__ aux){
  __shared__ int s[256];
  int t = threadIdx.x, i = blockIdx.x * 256 + t;
  int v = (i < N_NODES) ? deg[i] : 0;
  s[t] = v; __syncthreads();
  for (int off = 1; off < 256; off <<= 1){
    int x = (t >= off) ? s[t - off] : 0;
    __syncthreads();
    s[t] += x;
    __syncthreads();
  }
  if (i < N_NODES) tmp[i] = s[t];
  if (t == 255) aux[blockIdx.x] = s[255];
}

__global__ __launch_bounds__(1024) void k_scan2(int* __restrict__ aux, int n){
  __shared__ int s[1024];
  int t = threadIdx.x;
  int v = (t < n) ? aux[t] : 0;
  s[t] = v; __syncthreads();
  for (int off = 1; off < 1024; off <<= 1){
    int x = (t >= off) ? s[t - off] : 0;
    __syncthreads();
    s[t] += x;
    __syncthreads();
  }
  if (t < n) aux[t] = s[t] - v;   // exclusive
}

__global__ void k_rowptr(const int* __restrict__ tmp, const int* __restrict__ deg,
                         const int* __restrict__ aux, int* __restrict__ rp,
                         float* __restrict__ dis, int* __restrict__ gcur){
  int i = blockIdx.x * 256 + threadIdx.x;
  if (i < N_NODES){
    int v = aux[i >> 8] + tmp[i] - deg[i];
    rp[i] = v;
    int d = deg[i];
    dis[i] = (d > 0) ? (1.f / sqrtf((float)d)) : 0.f;
    if ((i & (PROWS - 1)) == 0) gcur[i >> PSHIFT] = v;  // partition append cursor
  }
  if (i == 0) rp[N_NODES] = N_EDGES;
}

// Counting-sort pass 1: per-block LDS histogram over 293 partitions, ONE
// global reservation per (block,partition), then scatter into block-exclusive
// contiguous runs.
__global__ __launch_bounds__(256) void k_part1(const int* __restrict__ h,
                                               const int* __restrict__ t,
                                               int* __restrict__ gcur,
                                               unsigned int* __restrict__ stg){
  __shared__ int hist[NPART];
  __shared__ int base[NPART];
  __shared__ int cnt2[NPART];
  int tid = threadIdx.x;
  int s = blockIdx.x * CHUNK;
  int e = min(s + CHUNK, N_EDGES);
  for (int p = tid; p < NPART; p += 256){ hist[p] = 0; cnt2[p] = 0; }
  __syncthreads();
  for (int i = s + tid; i < e; i += 256)
    atomicAdd(&hist[h[i] >> PSHIFT], 1);
  __syncthreads();
  for (int p = tid; p < NPART; p += 256){
    int c = hist[p];
    base[p] = c ? atomicAdd(&gcur[p], c) : 0;
  }
  __syncthreads();
  for (int i = s + tid; i < e; i += 256){
    int hh = h[i];
    int part = hh >> PSHIFT;
    int pos = base[part] + atomicAdd(&cnt2[part], 1);
    stg[pos] = ((unsigned)t[i] << PSHIFT) | (unsigned)(hh & (PROWS - 1));
  }
}

// Counting-sort pass 2: one block per partition.
__global__ __launch_bounds__(256) void k_part2(const int* __restrict__ rp,
                                               const unsigned int* __restrict__ stg,
                                               int* __restrict__ t_csr){
  __shared__ int cur[PROWS];
  int b = blockIdx.x, tid = threadIdx.x;
  int row0 = b << PSHIFT;
  int rows = min(PROWS, N_NODES - row0);
  for (int i = tid; i < rows; i += 256) cur[i] = rp[row0 + i];
  __syncthreads();
  int s = rp[row0], e = rp[row0 + rows];
  for (int i = s + tid; i < e; i += 256){
    unsigned int v = stg[i];
    int pos = atomicAdd(&cur[v & (PROWS - 1)], 1);
    t_csr[pos] = (int)(v >> PSHIFT);
  }
}

// gnn[n] = dis[n] * sum_e embd[t_e]  (embd = dis*emb premultiplied: the dis[t]
// gather line is gone -> 2 lines/edge). 8 edges in flight per wave, 16B loads.
// L2-normalized row -> fp8 lower half of the 128B hg record.
__global__ void k_spmm_gnn(const int* __restrict__ rp, const int* __restrict__ t_csr,
                           const float* __restrict__ dis,
                           const unsigned short* __restrict__ embd,
                           float* __restrict__ gnn, unsigned char* __restrict__ hg8){
  int w = (blockIdx.x * 256 + threadIdx.x) >> 6;
  int lane = threadIdx.x & 63;
  if (w >= N_NODES) return;
  int slot = lane >> 3, sub = lane & 7;      // 8 slots x 8 dims
  int s = rp[w], e = rp[w + 1];
  float a0=0.f,a1=0.f,a2=0.f,a3=0.f,a4=0.f,a5=0.f,a6=0.f,a7=0.f;
  for (int i = s + slot; i < e; i += 8){
    int t = t_csr[i];
    uint4 ev = *(const uint4*)(embd + (size_t)t * 64 + 8 * sub);
    a0 += bf_lo(ev.x); a1 += bf_hi(ev.x);
    a2 += bf_lo(ev.y); a3 += bf_hi(ev.y);
    a4 += bf_lo(ev.z); a5 += bf_hi(ev.z);
    a6 += bf_lo(ev.w); a7 += bf_hi(ev.w);
  }
#pragma unroll
  for (int m = 8; m <= 32; m <<= 1){
    a0 += __shfl_xor(a0, m, 64); a1 += __shfl_xor(a1, m, 64);
    a2 += __shfl_xor(a2, m, 64); a3 += __shfl_xor(a3, m, 64);
    a4 += __shfl_xor(a4, m, 64); a5 += __shfl_xor(a5, m, 64);
    a6 += __shfl_xor(a6, m, 64); a7 += __shfl_xor(a7, m, 64);
  }
  float dw = dis[w];
  float g0 = dw*a0, g1 = dw*a1, g2 = dw*a2, g3 = dw*a3;
  float g4 = dw*a4, g5 = dw*a5, g6 = dw*a6, g7 = dw*a7;
  float sq = g0*g0 + g1*g1 + g2*g2 + g3*g3 + g4*g4 + g5*g5 + g6*g6 + g7*g7;
#pragma unroll
  for (int m = 1; m <= 4; m <<= 1) sq += __shfl_xor(sq, m, 64);
  float invn = 1.f / fmaxf(sqrtf(sq), 1e-8f);
  if (slot == 0){
    float4 v0 = make_float4(g0, g1, g2, g3);
    float4 v1 = make_float4(g4, g5, g6, g7);
    ((float4*)gnn)[w * 16 + 2 * sub]     = v0;
    ((float4*)gnn)[w * 16 + 2 * sub + 1] = v1;
    unsigned int d0 = __builtin_amdgcn_cvt_pk_fp8_f32(g0*invn, g1*invn, 0, false);
    d0 = __builtin_amdgcn_cvt_pk_fp8_f32(g2*invn, g3*invn, d0, true);
    unsigned int d1 = __builtin_amdgcn_cvt_pk_fp8_f32(g4*invn, g5*invn, 0, false);
    d1 = __builtin_amdgcn_cvt_pk_fp8_f32(g6*invn, g7*invn, d1, true);
    uint2 o; o.x = d0; o.y = d1;
    *(uint2*)(hg8 + (size_t)w * 128 + 8 * sub) = o;   // lower 64B: hgA fp8
  }
}

// ---------------------------------------------------------------------------
// One-shot W preparation for the MFMA intent kernel (layout per R1 notes).
// ---------------------------------------------------------------------------
__global__ void k_wprep(const float* __restrict__ wu, const float* __restrict__ wi,
                        unsigned short* __restrict__ wbuf){
  const float* W = blockIdx.x ? wi : wu;
  unsigned short* seg = wbuf + blockIdx.x * 32768;
  int tid = threadIdx.x;
  for (int i = tid; i < DIM * N_INTENTS; i += 256){
    unsigned short h, l; split2(W[i], h, l);
    seg[16384 + i] = h; seg[24576 + i] = l;
  }
  for (int idx = tid; idx < 16 * 64; idx += 256){
    int f = idx >> 6, lane = idx & 63;
    int nt = f >> 1, ks = f & 1, g = lane >> 4, c = lane & 15;
    int in = 16 * nt + c;
#pragma unroll
    for (int e = 0; e < 8; e++){
      int d = 8 * g + e + 32 * ks;
      unsigned short h, l; split2(W[d * N_INTENTS + in], h, l);
      seg[f * 512 + lane * 8 + e] = h;
      seg[8192 + f * 512 + lane * 8 + e] = l;
    }
  }
}

// ---------------------------------------------------------------------------
// MFMA intent kernel: out = softmax(emb @ W) @ W^T, bf16 out + L2-norm as fp8
// into the UPPER 64B of the hg record. One 16-node tile per wave; no barriers.
// ---------------------------------------------------------------------------
__global__ __launch_bounds__(256) void k_intent_mfma(
    const unsigned short* __restrict__ wseg, const float* __restrict__ emb,
    unsigned short* __restrict__ out_bf, unsigned char* __restrict__ hg8,
    int base_node, int count){
  __shared__ __align__(16) unsigned int Pl[4][2048];   // 8KB per wave: P hi|lo packed
  int wid = threadIdx.x >> 6, lane = threadIdx.x & 63;
  int tile = blockIdx.x * 4 + wid;
  if (tile * 16 >= count) return;
  int g = lane >> 4, c = lane & 15;

  // ---- A-frags of E (hi/lo), node row = tile*16 + c, dims 8g..8g+7 (+32 for ks=1)
  const float4* erow = (const float4*)(emb + (size_t)(base_node + tile * 16 + c) * DIM);
  float4 ea0 = erow[2 * g],     eb0 = erow[2 * g + 1];
  float4 ea1 = erow[8 + 2 * g], eb1 = erow[9 + 2 * g];
  short8v ehi[2], elo[2];
  {
    float xs[16] = {ea0.x, ea0.y, ea0.z, ea0.w, eb0.x, eb0.y, eb0.z, eb0.w,
                    ea1.x, ea1.y, ea1.z, ea1.w, eb1.x, eb1.y, eb1.z, eb1.w};
#pragma unroll
    for (int ksi = 0; ksi < 2; ksi++)
#pragma unroll
      for (int e = 0; e < 8; e++){
        unsigned short h, l; split2(xs[ksi * 8 + e], h, l);
        ehi[ksi][e] = (short)h; elo[ksi][e] = (short)l;
      }
  }

  // ---- matmul1: L = E @ W  (8 n-tiles of 16 intents, K=64 in 2 steps)
  const uint4* w1hi = (const uint4*)wseg;
  const uint4* w1lo = (const uint4*)(wseg + 8192);
  f32x4 acc1[8];
#pragma unroll
  for (int nt = 0; nt < 8; nt++){
    f32x4 a = {0.f, 0.f, 0.f, 0.f};
#pragma unroll
    for (int ks = 0; ks < 2; ks++){
      short8v wh = __builtin_bit_cast(short8v, w1hi[(nt * 2 + ks) * 64 + lane]);
      short8v wl = __builtin_bit_cast(short8v, w1lo[(nt * 2 + ks) * 64 + lane]);
      a = __builtin_amdgcn_mfma_f32_16x16x32_bf16(ehi[ks], wh, a, 0, 0, 0);
      a = __builtin_amdgcn_mfma_f32_16x16x32_bf16(elo[ks], wh, a, 0, 0, 0);
      a = __builtin_amdgcn_mfma_f32_16x16x32_bf16(ehi[ks], wl, a, 0, 0, 0);
    }
    acc1[nt] = a;
  }

  // ---- softmax per node (row r of D = node 4g+r). Normalized P packed hi|lo
  // into wave-private LDS, XOR-swizzled for conflict-free frag reads.
  unsigned int* pw = &Pl[wid][0];
#pragma unroll
  for (int r = 0; r < 4; r++){
    float m = acc1[0][r];
#pragma unroll
    for (int nt = 1; nt < 8; nt++) m = fmaxf(m, acc1[nt][r]);
    m = row16_allmax(m);
    float p[8];
    float s = 0.f;
#pragma unroll
    for (int nt = 0; nt < 8; nt++){ p[nt] = __expf(acc1[nt][r] - m); s += p[nt]; }
    s = row16_allsum(s);
    float inv = 1.f / s;
    int node = 4 * g + r;
    int swz = (node & 7) << 2;
    int base = node * 128 + c;
#pragma unroll
    for (int nt = 0; nt < 8; nt++){
      float v = p[nt] * inv;
      unsigned short h, l; split2(v, h, l);
      pw[(base + 16 * nt) ^ swz] = (unsigned int)h | ((unsigned int)l << 16);
    }
  }

  // ---- A-frags of P for matmul2: node = c, intents 8g..8g+7 (+32*ks)
  const uint4* pr = (const uint4*)pw;
  short8v phf[4], plf[4];
  int sw = (c & 7) << 2;
#pragma unroll
  for (int ks = 0; ks < 4; ks++){
    int i0 = c * 128 + 8 * g + 32 * ks;
    uint4 ra = pr[(i0 ^ sw) >> 2];
    uint4 rb = pr[((i0 + 4) ^ sw) >> 2];
    unsigned int q[8] = {ra.x, ra.y, ra.z, ra.w, rb.x, rb.y, rb.z, rb.w};
#pragma unroll
    for (int e = 0; e < 8; e++){
      phf[ks][e] = (short)(q[e] & 0xFFFFu);
      plf[ks][e] = (short)(q[e] >> 16);
    }
  }

  // ---- matmul2: O = P @ W^T. B-frags of W^T are contiguous rows of
  // row-major bf16 W: row = 16*nt + c, cols 8g..8g+7 (+32*ks).
  const uint4* w2hi = (const uint4*)(wseg + 16384);
  const uint4* w2lo = (const uint4*)(wseg + 24576);
  f32x4 acc2[4];
#pragma unroll
  for (int nt = 0; nt < 4; nt++){
    f32x4 a = {0.f, 0.f, 0.f, 0.f};
#pragma unroll
    for (int ks = 0; ks < 4; ks++){
      int fi = (16 * nt + c) * 16 + ks * 4 + g;
      short8v wh = __builtin_bit_cast(short8v, w2hi[fi]);
      short8v wl = __builtin_bit_cast(short8v, w2lo[fi]);
      a = __builtin_amdgcn_mfma_f32_16x16x32_bf16(phf[ks], wh, a, 0, 0, 0);
      a = __builtin_amdgcn_mfma_f32_16x16x32_bf16(plf[ks], wh, a, 0, 0, 0);
      a = __builtin_amdgcn_mfma_f32_16x16x32_bf16(phf[ks], wl, a, 0, 0, 0);
    }
    acc2[nt] = a;
  }

  // ---- outputs: D[m=4g+r][n=c] -> node 4g+r, dim 16*nt + c.
#pragma unroll
  for (int r = 0; r < 4; r++){
    float sq = 0.f;
#pragma unroll
    for (int nt = 0; nt < 4; nt++) sq = fmaf(acc2[nt][r], acc2[nt][r], sq);
    sq = row16_allsum(sq);
    float invn = 1.f / fmaxf(sqrtf(sq), 1e-8f);
    size_t node = (size_t)(base_node + tile * 16 + 4 * g + r);
    unsigned char* hw = hg8 + node * 128 + 64;   // upper 64B: hgB fp8
    size_t obase = node * DIM + c;
#pragma unroll
    for (int nt = 0; nt < 4; nt++){
      float v = acc2[nt][r];
      out_bf[obase + 16 * nt] = f2bf(v);
      hw[16 * nt + c] = f2fp8(v * invn);
    }
  }
}

// ---------------------------------------------------------------------------
// Fused adaptive passes + residual + acc + bf16 emb/embd for next layer.
// Occupancy-first: 4 edge slots/wave; per edge per lane ONE uint2 from the
// 128B fp8 hg record (subs 0-7 = hgA dims, 8-15 = hgB dims; HW cvt decode)
// + ONE uint2 of embb values -> 4 cache lines/edge (was 6). Dual cosine via
// 8-lane butterfly + xor-8 exchange (4 cross-lane ops).
// ---------------------------------------------------------------------------
__global__ void k_adafuse(const int* __restrict__ rp, const int* __restrict__ t_csr,
                          const unsigned char* __restrict__ hg8,
                          const uint2* __restrict__ inte_bf2,
                          const uint2* __restrict__ embb2,
                          const float* __restrict__ emb,
                          const float* __restrict__ dis,
                          float* __restrict__ gnn_io, float* __restrict__ acc,
                          uint2* __restrict__ embb_next2,
                          uint2* __restrict__ embd_next2){
  int w = (blockIdx.x * 256 + threadIdx.x) >> 6;
  int lane = threadIdx.x & 63;
  if (w >= N_NODES) return;
  int slot = lane >> 4, sub = lane & 15;
  const uint2* hg2 = (const uint2*)hg8;
  // own record: lane holds 8 fp8 dims of hgA (sub<8) or hgB (sub>=8)
  float wv[8];
  fp8dec8(hg2[(size_t)w * 16 + sub], wv);
  bool isA = sub < 8;
  int s = rp[w], e = rp[w + 1];
  float4 s1 = make_float4(0.f, 0.f, 0.f, 0.f);
  float4 s2 = make_float4(0.f, 0.f, 0.f, 0.f);
  float r1 = 0.f, r2 = 0.f;
  for (int i = s + slot; i < e; i += 4){
    int t = t_csr[i];
    float tv[8];
    fp8dec8(hg2[(size_t)t * 16 + sub], tv);
    float part = wv[0]*tv[0] + wv[1]*tv[1] + wv[2]*tv[2] + wv[3]*tv[3]
               + wv[4]*tv[4] + wv[5]*tv[5] + wv[6]*tv[6] + wv[7]*tv[7];
    part += __shfl_xor(part, 1, 64);
    part += __shfl_xor(part, 2, 64);
    part += __shfl_xor(part, 4, 64);      // 8-group sums
    float other = __shfl_xor(part, 8, 64);
    float p = isA ? part : other;         // A-cosine
    float q = isA ? other : part;         // B-cosine
    float a1 = fmaf(p, 0.5f, 0.5f);
    float a2 = fmaf(q, 0.5f, 0.5f);
    r1 += a1; r2 += a2;
    uint2 ev = embb2[(size_t)t * 16 + sub];
    float v0 = bf_lo(ev.x), v1 = bf_hi(ev.x), v2 = bf_lo(ev.y), v3 = bf_hi(ev.y);
    s1.x = fmaf(a1, v0, s1.x); s1.y = fmaf(a1, v1, s1.y);
    s1.z = fmaf(a1, v2, s1.z); s1.w = fmaf(a1, v3, s1.w);
    s2.x = fmaf(a2, v0, s2.x); s2.y = fmaf(a2, v1, s2.y);
    s2.z = fmaf(a2, v2, s2.z); s2.w = fmaf(a2, v3, s2.w);
  }
#pragma unroll
  for (int m = 16; m <= 32; m <<= 1){
    s1.x += __shfl_xor(s1.x, m, 64); s1.y += __shfl_xor(s1.y, m, 64);
    s1.z += __shfl_xor(s1.z, m, 64); s1.w += __shfl_xor(s1.w, m, 64);
    s2.x += __shfl_xor(s2.x, m, 64); s2.y += __shfl_xor(s2.y, m, 64);
    s2.z += __shfl_xor(s2.z, m, 64); s2.w += __shfl_xor(s2.w, m, 64);
    r1   += __shfl_xor(r1,   m, 64); r2   += __shfl_xor(r2,   m, 64);
  }
  float d1 = (r1 > 0.f) ? 1.f / r1 : 0.f;
  float d2 = (r2 > 0.f) ? 1.f / r2 : 0.f;
  if (slot == 0){
    int idx4 = w * 16 + sub;
    float4 gg = ((float4*)gnn_io)[idx4];
    uint2 it = inte_bf2[idx4];
    float4 em = ((const float4*)emb)[idx4];
    float4 nv;
    nv.x = gg.x + bf_lo(it.x) + em.x + d1 * s1.x + d2 * s2.x;
    nv.y = gg.y + bf_hi(it.x) + em.y + d1 * s1.y + d2 * s2.y;
    nv.z = gg.z + bf_lo(it.y) + em.z + d1 * s1.z + d2 * s2.z;
    nv.w = gg.w + bf_hi(it.y) + em.w + d1 * s1.w + d2 * s2.w;
    ((float4*)gnn_io)[idx4] = nv;
    float4 ac = ((float4*)acc)[idx4];
    ac.x += nv.x; ac.y += nv.y; ac.z += nv.z; ac.w += nv.w;
    ((float4*)acc)[idx4] = ac;
    uint2 ob;
    ob.x = (unsigned)f2bf(nv.x) | ((unsigned)f2bf(nv.y) << 16);
    ob.y = (unsigned)f2bf(nv.z) | ((unsigned)f2bf(nv.w) << 16);
    embb_next2[idx4] = ob;   // bf16 emb for next layer (other buffer: no race)
    float dw = dis[w];
    uint2 od;
    od.x = (unsigned)f2bf(dw * nv.x) | ((unsigned)f2bf(dw * nv.y) << 16);
    od.y = (unsigned)f2bf(dw * nv.z) | ((unsigned)f2bf(dw * nv.w) << 16);
    embd_next2[idx4] = od;   // premultiplied gather array for next spmm
  }
}

extern "C" void kernel_launch(void* const* d_in, const int* in_sizes, int n_in,
                              void* d_out, int out_size, void* d_ws, size_t ws_size,
                              hipStream_t stream){
  const float* ue = (const float*)d_in[0];
  const float* ie = (const float*)d_in[1];
  const float* wu = (const float*)d_in[2];
  const float* wi = (const float*)d_in[3];
  const int* all_h = (const int*)d_in[4];
  const int* all_t = (const int*)d_in[5];
  float* acc = (float*)d_out;

  char* p = (char*)d_ws;
  auto take = [&](size_t bytes)->char*{
    char* r = p; p += (bytes + 255) & ~size_t(255); return r;
  };
  float*  embA  = (float*)take(sizeof(float) * N_NODES * DIM);
  float*  embB  = (float*)take(sizeof(float) * N_NODES * DIM);
  unsigned char* hg8 = (unsigned char*)take((size_t)N_NODES * 128);
  unsigned short* inte_bf = (unsigned short*)take(sizeof(short) * N_NODES * DIM);
  unsigned short* embbA   = (unsigned short*)take(sizeof(short) * N_NODES * DIM);
  unsigned short* embbB   = (unsigned short*)take(sizeof(short) * N_NODES * DIM);
  unsigned short* embd    = (unsigned short*)take(sizeof(short) * N_NODES * DIM);
  unsigned short* wbuf    = (unsigned short*)take(sizeof(short) * 2 * 32768);
  int*    t_csr = (int*)take(sizeof(int) * N_EDGES);
  float*  dis   = (float*)take(sizeof(float) * N_NODES);
  int*    deg   = (int*)take(sizeof(int) * N_NODES);
  int*    tmp   = (int*)take(sizeof(int) * N_NODES);
  int*    aux   = (int*)take(sizeof(int) * 1024);
  int*    rp    = (int*)take(sizeof(int) * (N_NODES + 1));
  int*    gcur  = (int*)take(sizeof(int) * NPART);
  if ((size_t)(p - (char*)d_ws) > ws_size) return;
  // staging (12 MB) aliases hg8 (19.2 MB): only live before spmm writes hg8
  unsigned int* stg = (unsigned int*)hg8;

  const int ELEM_B  = (N_NODES * DIM + 255) / 256;
  const int ELEM4_B = (N_NODES * 16 + 255) / 256;
  const int NODEW_B = (N_NODES * 64 + 255) / 256;
  const int EDGE_B  = (N_EDGES + 255) / 256;
  const int NODE_B  = (N_NODES + 255) / 256;

  hipMemsetAsync(deg, 0, sizeof(int) * N_NODES, stream);
  k_init<<<ELEM_B, 256, 0, stream>>>(ue, ie, embA, acc, embbA);
  k_wprep<<<2, 256, 0, stream>>>(wu, wi, wbuf);
  k_deg<<<EDGE_B, 256, 0, stream>>>(all_h, deg);
  k_scan1<<<NODE_B, 256, 0, stream>>>(deg, tmp, aux);
  k_scan2<<<1, 1024, 0, stream>>>(aux, NODE_B);
  k_rowptr<<<NODE_B, 256, 0, stream>>>(tmp, deg, aux, rp, dis, gcur);
  k_embd0<<<ELEM4_B, 256, 0, stream>>>(embA, dis, (uint2*)embd);
  k_part1<<<NCHB, 256, 0, stream>>>(all_h, all_t, gcur, stg);
  k_part2<<<NPART, 256, 0, stream>>>(rp, stg, t_csr);

  const int UT_B = ((N_USERS / 16) + 3) / 4;   // user tiles -> blocks
  const int IT_B = ((N_ITEMS / 16) + 3) / 4;   // item tiles -> blocks

  float* eA = embA;
  float* eB = embB;
  unsigned short* ebA = embbA;  // bf16 of current emb
  unsigned short* ebB = embbB;
  for (int layer = 0; layer < 2; layer++){
    k_spmm_gnn<<<NODEW_B, 256, 0, stream>>>(rp, t_csr, dis, embd, eB, hg8);
    k_intent_mfma<<<UT_B, 256, 0, stream>>>(wbuf, eA, inte_bf, hg8, 0, N_USERS);
    k_intent_mfma<<<IT_B, 256, 0, stream>>>(wbuf + 32768, eA, inte_bf, hg8,
                                            N_USERS, N_ITEMS);
    k_adafuse<<<NODEW_B, 256, 0, stream>>>(rp, t_csr, hg8,
                                           (const uint2*)inte_bf,
                                           (const uint2*)ebA,
                                           eA, dis, eB, acc,
                                           (uint2*)ebB, (uint2*)embd);
    float* t = eA; eA = eB; eB = t;
    unsigned short* tb = ebA; ebA = ebB; ebB = tb;
  }
}

// Round 8
// 937.897 us; speedup vs baseline: 1.1663x; 1.0117x over previous
//
#include <hip/hip_runtime.h>
#include <hip/hip_bf16.h>

#define N_USERS   50000
#define N_ITEMS   100000
#define N_NODES   150000
#define DIM       64
#define N_INTENTS 128
#define N_EDGES   3000000
#define PSHIFT    9                         // 512 rows per partition
#define PROWS     (1 << PSHIFT)
#define NPART     ((N_NODES + PROWS - 1) >> PSHIFT)   // 293
#define CHUNK     16384                     // edges per binning block
#define NCHB      ((N_EDGES + CHUNK - 1) / CHUNK)     // 184
#define RECB      256   // per-node record: hgA fp8 64 | hgB fp8 64 | emb bf16 128

#define UT_TILES  (N_USERS / 16)             // 3125
#define TOT_TILES ((N_USERS + N_ITEMS) / 16) // 9375
#define INT_B     ((TOT_TILES + 3) / 4)      // 2344

typedef __attribute__((ext_vector_type(8))) short short8v;  // 8 bf16 (4 VGPRs)
typedef __attribute__((ext_vector_type(4))) float f32x4;
typedef __attribute__((ext_vector_type(2))) float f32x2;

// ---- DPP 16-lane row reduction (full-rate VALU)
template<int CTRL>
static __device__ __forceinline__ float dpp_ror_add(float x){
  int t = __builtin_amdgcn_update_dpp(0, __builtin_bit_cast(int, x),
                                      CTRL, 0xF, 0xF, true);
  return x + __builtin_bit_cast(float, t);
}
static __device__ __forceinline__ float row16_allsum(float x){
  x = dpp_ror_add<0x128>(x);  // row_ror:8
  x = dpp_ror_add<0x124>(x);  // row_ror:4
  x = dpp_ror_add<0x122>(x);  // row_ror:2
  x = dpp_ror_add<0x121>(x);  // row_ror:1
  return x;
}
template<int CTRL>
static __device__ __forceinline__ float dpp_ror_max(float x){
  int t = __builtin_amdgcn_update_dpp(0, __builtin_bit_cast(int, x),
                                      CTRL, 0xF, 0xF, true);
  return fmaxf(x, __builtin_bit_cast(float, t));
}
static __device__ __forceinline__ float row16_allmax(float x){
  x = dpp_ror_max<0x128>(x);
  x = dpp_ror_max<0x124>(x);
  x = dpp_ror_max<0x122>(x);
  x = dpp_ror_max<0x121>(x);
  return x;
}

// bf16 pack/unpack
static __device__ __forceinline__ unsigned short f2bf(float x){
  __hip_bfloat16 h = __float2bfloat16(x);
  return __builtin_bit_cast(unsigned short, h);
}
static __device__ __forceinline__ float bf_lo(unsigned int v){
  return __builtin_bit_cast(float, v << 16);
}
static __device__ __forceinline__ float bf_hi(unsigned int v){
  return __builtin_bit_cast(float, v & 0xFFFF0000u);
}
static __device__ __forceinline__ float bfval(unsigned short h){
  return __builtin_bit_cast(float, (unsigned int)h << 16);
}
// hi/lo bf16 split: x ~= bf(hi) + bf(lo), rel err ~2^-17 (fp32-fidelity for MFMA)
static __device__ __forceinline__ void split2(float x, unsigned short& hi,
                                              unsigned short& lo){
  hi = f2bf(x);
  lo = f2bf(x - bfval(hi));
}

// ---- fp8 (OCP e4m3) HW converts.
static __device__ __forceinline__ void fp8dec8(uint2 v, float* f){
  f32x2 a = __builtin_amdgcn_cvt_pk_f32_fp8(v.x, false);
  f32x2 b = __builtin_amdgcn_cvt_pk_f32_fp8(v.x, true);
  f32x2 c = __builtin_amdgcn_cvt_pk_f32_fp8(v.y, false);
  f32x2 d = __builtin_amdgcn_cvt_pk_f32_fp8(v.y, true);
  f[0]=a[0]; f[1]=a[1]; f[2]=b[0]; f[3]=b[1];
  f[4]=c[0]; f[5]=c[1]; f[6]=d[0]; f[7]=d[1];
}
static __device__ __forceinline__ unsigned int fp8pack4(float a, float b,
                                                        float c, float d){
  unsigned int v = __builtin_amdgcn_cvt_pk_fp8_f32(a, b, 0, false);
  return __builtin_amdgcn_cvt_pk_fp8_f32(c, d, v, true);
}
static __device__ __forceinline__ unsigned char f2fp8(float x){
  return (unsigned char)(__builtin_amdgcn_cvt_pk_fp8_f32(x, x, 0, false) & 0xFF);
}

// emb = concat(user_emb, item_emb); acc(=d_out) = emb
__global__ void k_init(const float* __restrict__ ue, const float* __restrict__ ie,
                       float* __restrict__ emb, float* __restrict__ acc){
  int i = blockIdx.x * 256 + threadIdx.x;
  if (i >= N_NODES * DIM) return;
  float v = (i < N_USERS * DIM) ? ue[i] : ie[i - N_USERS * DIM];
  emb[i] = v; acc[i] = v;
}

// embd[n][d] = bf16(dis[n]*emb[n][d]); rec0 emb-segment = bf16(emb[n][d])
__global__ void k_embd0(const float* __restrict__ emb, const float* __restrict__ dis,
                        uint2* __restrict__ embd2, unsigned char* __restrict__ rec0){
  int i = blockIdx.x * 256 + threadIdx.x;     // over N_NODES*16 float4 groups
  if (i >= N_NODES * 16) return;
  int n = i >> 4, sub = i & 15;
  float d = dis[n];
  float4 v = ((const float4*)emb)[i];
  uint2 ob;
  ob.x = (unsigned)f2bf(d * v.x) | ((unsigned)f2bf(d * v.y) << 16);
  ob.y = (unsigned)f2bf(d * v.z) | ((unsigned)f2bf(d * v.w) << 16);
  embd2[i] = ob;
  uint2 eb;
  eb.x = (unsigned)f2bf(v.x) | ((unsigned)f2bf(v.y) << 16);
  eb.y = (unsigned)f2bf(v.z) | ((unsigned)f2bf(v.w) << 16);
  *(uint2*)(rec0 + (size_t)n * RECB + 128 + 8 * sub) = eb;
}

__global__ void k_deg(const int* __restrict__ h, int* __restrict__ deg){
  int e = blockIdx.x * 256 + threadIdx.x;
  if (e < N_EDGES) atomicAdd(&deg[h[e]], 1);
}

__global__ void k_scan1(const int* __restrict__ deg, int* __restrict__ tmp,
                        int* __restrict__ aux){
  __shared__ int s[256];
  int t = threadIdx.x, i = blockIdx.x * 256 + t;
  int v = (i < N_NODES) ? deg[i] : 0;
  s[t] = v; __syncthreads();
  for (int off = 1; off < 256; off <<= 1){
    int x = (t >= off) ? s[t - off] : 0;
    __syncthreads();
    s[t] += x;
    __syncthreads();
  }
  if (i < N_NODES) tmp[i] = s[t];
  if (t == 255) aux[blockIdx.x] = s[255];
}

__global__ __launch_bounds__(1024) void k_scan2(int* __restrict__ aux, int n){
  __shared__ int s[1024];
  int t = threadIdx.x;
  int v = (t < n) ? aux[t] : 0;
  s[t] = v; __syncthreads();
  for (int off = 1; off < 1024; off <<= 1){
    int x = (t >= off) ? s[t - off] : 0;
    __syncthreads();
    s[t] += x;
    __syncthreads();
  }
  if (t < n) aux[t] = s[t] - v;   // exclusive
}

__global__ void k_rowptr(const int* __restrict__ tmp, const int* __restrict__ deg,
                         const int* __restrict__ aux, int* __restrict__ rp,
                         float* __restrict__ dis, int* __restrict__ gcur){
  int i = blockIdx.x * 256 + threadIdx.x;
  if (i < N_NODES){
    int v = aux[i >> 8] + tmp[i] - deg[i];
    rp[i] = v;
    int d = deg[i];
    dis[i] = (d > 0) ? (1.f / sqrtf((float)d)) : 0.f;
    if ((i & (PROWS - 1)) == 0) gcur[i >> PSHIFT] = v;  // partition append cursor
  }
  if (i == 0) rp[N_NODES] = N_EDGES;
}

// Counting-sort pass 1: per-block LDS histogram over 293 partitions, ONE
// global reservation per (block,partition), then scatter into block-exclusive
// contiguous runs.
__global__ __launch_bounds__(256) void k_part1(const int* __restrict__ h,
                                               const int* __restrict__ t,
                                               int* __restrict__ gcur,
                                               unsigned int* __restrict__ stg){
  __shared__ int hist[NPART];
  __shared__ int base[NPART];
  __shared__ int cnt2[NPART];
  int tid = threadIdx.x;
  int s = blockIdx.x * CHUNK;
  int e = min(s + CHUNK, N_EDGES);
  for (int p = tid; p < NPART; p += 256){ hist[p] = 0; cnt2[p] = 0; }
  __syncthreads();
  for (int i = s + tid; i < e; i += 256)
    atomicAdd(&hist[h[i] >> PSHIFT], 1);
  __syncthreads();
  for (int p = tid; p < NPART; p += 256){
    int c = hist[p];
    base[p] = c ? atomicAdd(&gcur[p], c) : 0;
  }
  __syncthreads();
  for (int i = s + tid; i < e; i += 256){
    int hh = h[i];
    int part = hh >> PSHIFT;
    int pos = base[part] + atomicAdd(&cnt2[part], 1);
    stg[pos] = ((unsigned)t[i] << PSHIFT) | (unsigned)(hh & (PROWS - 1));
  }
}

// Counting-sort pass 2: one block per partition.
__global__ __launch_bounds__(256) void k_part2(const int* __restrict__ rp,
                                               const unsigned int* __restrict__ stg,
                                               int* __restrict__ t_csr){
  __shared__ int cur[PROWS];
  int b = blockIdx.x, tid = threadIdx.x;
  int row0 = b << PSHIFT;
  int rows = min(PROWS, N_NODES - row0);
  for (int i = tid; i < rows; i += 256) cur[i] = rp[row0 + i];
  __syncthreads();
  int s = rp[row0], e = rp[row0 + rows];
  for (int i = s + tid; i < e; i += 256){
    unsigned int v = stg[i];
    int pos = atomicAdd(&cur[v & (PROWS - 1)], 1);
    t_csr[pos] = (int)(v >> PSHIFT);
  }
}

// gnn[n] = dis[n] * sum_e embd[t_e] (premultiplied). 8 edges in flight/wave,
// 16B loads. L2-normalized row -> fp8 hgA segment of the 256B record.
__global__ void k_spmm_gnn(const int* __restrict__ rp, const int* __restrict__ t_csr,
                           const float* __restrict__ dis,
                           const unsigned short* __restrict__ embd,
                           float* __restrict__ gnn, unsigned char* __restrict__ rec){
  int w = (blockIdx.x * 256 + threadIdx.x) >> 6;
  int lane = threadIdx.x & 63;
  if (w >= N_NODES) return;
  int slot = lane >> 3, sub = lane & 7;      // 8 slots x 8 dims
  int s = rp[w], e = rp[w + 1];
  float a0=0.f,a1=0.f,a2=0.f,a3=0.f,a4=0.f,a5=0.f,a6=0.f,a7=0.f;
  for (int i = s + slot; i < e; i += 8){
    int t = t_csr[i];
    uint4 ev = *(const uint4*)(embd + (size_t)t * 64 + 8 * sub);
    a0 += bf_lo(ev.x); a1 += bf_hi(ev.x);
    a2 += bf_lo(ev.y); a3 += bf_hi(ev.y);
    a4 += bf_lo(ev.z); a5 += bf_hi(ev.z);
    a6 += bf_lo(ev.w); a7 += bf_hi(ev.w);
  }
#pragma unroll
  for (int m = 8; m <= 32; m <<= 1){
    a0 += __shfl_xor(a0, m, 64); a1 += __shfl_xor(a1, m, 64);
    a2 += __shfl_xor(a2, m, 64); a3 += __shfl_xor(a3, m, 64);
    a4 += __shfl_xor(a4, m, 64); a5 += __shfl_xor(a5, m, 64);
    a6 += __shfl_xor(a6, m, 64); a7 += __shfl_xor(a7, m, 64);
  }
  float dw = dis[w];
  float g0 = dw*a0, g1 = dw*a1, g2 = dw*a2, g3 = dw*a3;
  float g4 = dw*a4, g5 = dw*a5, g6 = dw*a6, g7 = dw*a7;
  float sq = g0*g0 + g1*g1 + g2*g2 + g3*g3 + g4*g4 + g5*g5 + g6*g6 + g7*g7;
#pragma unroll
  for (int m = 1; m <= 4; m <<= 1) sq += __shfl_xor(sq, m, 64);
  float invn = 1.f / fmaxf(sqrtf(sq), 1e-8f);
  if (slot == 0){
    float4 v0 = make_float4(g0, g1, g2, g3);
    float4 v1 = make_float4(g4, g5, g6, g7);
    ((float4*)gnn)[w * 16 + 2 * sub]     = v0;
    ((float4*)gnn)[w * 16 + 2 * sub + 1] = v1;
    uint2 o;
    o.x = fp8pack4(g0*invn, g1*invn, g2*invn, g3*invn);
    o.y = fp8pack4(g4*invn, g5*invn, g6*invn, g7*invn);
    *(uint2*)(rec + (size_t)w * RECB + 8 * sub) = o;   // hgA segment
  }
}

// ---------------------------------------------------------------------------
// One-shot W preparation for the MFMA intent kernel (layout per R1 notes).
// ---------------------------------------------------------------------------
__global__ void k_wprep(const float* __restrict__ wu, const float* __restrict__ wi,
                        unsigned short* __restrict__ wbuf){
  const float* W = blockIdx.x ? wi : wu;
  unsigned short* seg = wbuf + blockIdx.x * 32768;
  int tid = threadIdx.x;
  for (int i = tid; i < DIM * N_INTENTS; i += 256){
    unsigned short h, l; split2(W[i], h, l);
    seg[16384 + i] = h; seg[24576 + i] = l;
  }
  for (int idx = tid; idx < 16 * 64; idx += 256){
    int f = idx >> 6, lane = idx & 63;
    int nt = f >> 1, ks = f & 1, g = lane >> 4, c = lane & 15;
    int in = 16 * nt + c;
#pragma unroll
    for (int e = 0; e < 8; e++){
      int d = 8 * g + e + 32 * ks;
      unsigned short h, l; split2(W[d * N_INTENTS + in], h, l);
      seg[f * 512 + lane * 8 + e] = h;
      seg[8192 + f * 512 + lane * 8 + e] = l;
    }
  }
}

// ---------------------------------------------------------------------------
// MFMA intent kernel (users+items in ONE launch): out = softmax(emb@W)@W^T,
// bf16 out + L2-norm as fp8 into the hgB segment. One 16-node tile per wave.
// ---------------------------------------------------------------------------
__global__ __launch_bounds__(256) void k_intent_mfma(
    const unsigned short* __restrict__ wbuf, const float* __restrict__ emb,
    unsigned short* __restrict__ out_bf, unsigned char* __restrict__ rec){
  __shared__ __align__(16) unsigned int Pl[4][2048];   // 8KB per wave: P hi|lo packed
  int wid = threadIdx.x >> 6, lane = threadIdx.x & 63;
  int tile = blockIdx.x * 4 + wid;
  if (tile >= TOT_TILES) return;
  int node0; const unsigned short* wseg;
  if (tile < UT_TILES){ node0 = tile * 16;                         wseg = wbuf; }
  else                { node0 = N_USERS + (tile - UT_TILES) * 16;  wseg = wbuf + 32768; }
  int g = lane >> 4, c = lane & 15;

  // ---- A-frags of E (hi/lo), node row = node0 + c, dims 8g..8g+7 (+32 for ks=1)
  const float4* erow = (const float4*)(emb + (size_t)(node0 + c) * DIM);
  float4 ea0 = erow[2 * g],     eb0 = erow[2 * g + 1];
  float4 ea1 = erow[8 + 2 * g], eb1 = erow[9 + 2 * g];
  short8v ehi[2], elo[2];
  {
    float xs[16] = {ea0.x, ea0.y, ea0.z, ea0.w, eb0.x, eb0.y, eb0.z, eb0.w,
                    ea1.x, ea1.y, ea1.z, ea1.w, eb1.x, eb1.y, eb1.z, eb1.w};
#pragma unroll
    for (int ksi = 0; ksi < 2; ksi++)
#pragma unroll
      for (int e = 0; e < 8; e++){
        unsigned short h, l; split2(xs[ksi * 8 + e], h, l);
        ehi[ksi][e] = (short)h; elo[ksi][e] = (short)l;
      }
  }

  // ---- matmul1: L = E @ W  (8 n-tiles of 16 intents, K=64 in 2 steps)
  const uint4* w1hi = (const uint4*)wseg;
  const uint4* w1lo = (const uint4*)(wseg + 8192);
  f32x4 acc1[8];
#pragma unroll
  for (int nt = 0; nt < 8; nt++){
    f32x4 a = {0.f, 0.f, 0.f, 0.f};
#pragma unroll
    for (int ks = 0; ks < 2; ks++){
      short8v wh = __builtin_bit_cast(short8v, w1hi[(nt * 2 + ks) * 64 + lane]);
      short8v wl = __builtin_bit_cast(short8v, w1lo[(nt * 2 + ks) * 64 + lane]);
      a = __builtin_amdgcn_mfma_f32_16x16x32_bf16(ehi[ks], wh, a, 0, 0, 0);
      a = __builtin_amdgcn_mfma_f32_16x16x32_bf16(elo[ks], wh, a, 0, 0, 0);
      a = __builtin_amdgcn_mfma_f32_16x16x32_bf16(ehi[ks], wl, a, 0, 0, 0);
    }
    acc1[nt] = a;
  }

  // ---- softmax per node (row r of D = node 4g+r). Normalized P packed hi|lo
  // into wave-private LDS, XOR-swizzled for conflict-free frag reads.
  unsigned int* pw = &Pl[wid][0];
#pragma unroll
  for (int r = 0; r < 4; r++){
    float m = acc1[0][r];
#pragma unroll
    for (int nt = 1; nt < 8; nt++) m = fmaxf(m, acc1[nt][r]);
    m = row16_allmax(m);
    float p[8];
    float s = 0.f;
#pragma unroll
    for (int nt = 0; nt < 8; nt++){ p[nt] = __expf(acc1[nt][r] - m); s += p[nt]; }
    s = row16_allsum(s);
    float inv = 1.f / s;
    int node = 4 * g + r;
    int swz = (node & 7) << 2;
    int base = node * 128 + c;
#pragma unroll
    for (int nt = 0; nt < 8; nt++){
      float v = p[nt] * inv;
      unsigned short h, l; split2(v, h, l);
      pw[(base + 16 * nt) ^ swz] = (unsigned int)h | ((unsigned int)l << 16);
    }
  }

  // ---- A-frags of P for matmul2: node = c, intents 8g..8g+7 (+32*ks)
  const uint4* pr = (const uint4*)pw;
  short8v phf[4], plf[4];
  int sw = (c & 7) << 2;
#pragma unroll
  for (int ks = 0; ks < 4; ks++){
    int i0 = c * 128 + 8 * g + 32 * ks;
    uint4 ra = pr[(i0 ^ sw) >> 2];
    uint4 rb = pr[((i0 + 4) ^ sw) >> 2];
    unsigned int q[8] = {ra.x, ra.y, ra.z, ra.w, rb.x, rb.y, rb.z, rb.w};
#pragma unroll
    for (int e = 0; e < 8; e++){
      phf[ks][e] = (short)(q[e] & 0xFFFFu);
      plf[ks][e] = (short)(q[e] >> 16);
    }
  }

  // ---- matmul2: O = P @ W^T. B-frags of W^T are contiguous rows of
  // row-major bf16 W: row = 16*nt + c, cols 8g..8g+7 (+32*ks).
  const uint4* w2hi = (const uint4*)(wseg + 16384);
  const uint4* w2lo = (const uint4*)(wseg + 24576);
  f32x4 acc2[4];
#pragma unroll
  for (int nt = 0; nt < 4; nt++){
    f32x4 a = {0.f, 0.f, 0.f, 0.f};
#pragma unroll
    for (int ks = 0; ks < 4; ks++){
      int fi = (16 * nt + c) * 16 + ks * 4 + g;
      short8v wh = __builtin_bit_cast(short8v, w2hi[fi]);
      short8v wl = __builtin_bit_cast(short8v, w2lo[fi]);
      a = __builtin_amdgcn_mfma_f32_16x16x32_bf16(phf[ks], wh, a, 0, 0, 0);
      a = __builtin_amdgcn_mfma_f32_16x16x32_bf16(plf[ks], wh, a, 0, 0, 0);
      a = __builtin_amdgcn_mfma_f32_16x16x32_bf16(phf[ks], wl, a, 0, 0, 0);
    }
    acc2[nt] = a;
  }

  // ---- outputs: D[m=4g+r][n=c] -> node 4g+r, dim 16*nt + c.
#pragma unroll
  for (int r = 0; r < 4; r++){
    float sq = 0.f;
#pragma unroll
    for (int nt = 0; nt < 4; nt++) sq = fmaf(acc2[nt][r], acc2[nt][r], sq);
    sq = row16_allsum(sq);
    float invn = 1.f / fmaxf(sqrtf(sq), 1e-8f);
    size_t node = (size_t)(node0 + 4 * g + r);
    unsigned char* hw = rec + node * RECB + 64;   // hgB segment
    size_t obase = node * DIM + c;
#pragma unroll
    for (int nt = 0; nt < 4; nt++){
      float v = acc2[nt][r];
      out_bf[obase + 16 * nt] = f2bf(v);
      hw[16 * nt + c] = f2fp8(v * invn);
    }
  }
}

// ---------------------------------------------------------------------------
// Fused adaptive passes + residual + acc + next-layer emb derivatives.
// Per edge, ONE record base: 256B = 4 consecutive lines (hgA|hgB fp8, emb
// bf16). Lane sub reads uint2 of hg (sub<8: A dims, >=8: B dims) + uint2 of
// bf16 emb (dims 4sub..4sub+3). Dual cosine via 8-lane butterfly + xor-8.
// Occupancy-first: no pipeline, no MFMA, no LDS.
// ---------------------------------------------------------------------------
__global__ void k_adafuse(const int* __restrict__ rp, const int* __restrict__ t_csr,
                          const unsigned char* __restrict__ rec,
                          const uint2* __restrict__ inte_bf2,
                          const float* __restrict__ emb,
                          const float* __restrict__ dis,
                          float* __restrict__ gnn_io, float* __restrict__ acc,
                          uint2* __restrict__ embd_next2,
                          unsigned char* __restrict__ rec_next,
                          int write_next){
  int w = (blockIdx.x * 256 + threadIdx.x) >> 6;
  int lane = threadIdx.x & 63;
  if (w >= N_NODES) return;
  int slot = lane >> 4, sub = lane & 15;
  // own record: lane holds 8 fp8 dims of hgA (sub<8) or hgB (sub>=8)
  const unsigned char* wrec = rec + (size_t)w * RECB;
  float wv[8];
  fp8dec8(*(const uint2*)(wrec + 8 * sub), wv);
  bool isA = sub < 8;
  int s = rp[w], e = rp[w + 1];
  float4 s1 = make_float4(0.f, 0.f, 0.f, 0.f);
  float4 s2 = make_float4(0.f, 0.f, 0.f, 0.f);
  float r1 = 0.f, r2 = 0.f;
  for (int i = s + slot; i < e; i += 4){
    int t = t_csr[i];
    const unsigned char* tr = rec + (size_t)t * RECB;
    float tv[8];
    fp8dec8(*(const uint2*)(tr + 8 * sub), tv);
    float part = wv[0]*tv[0] + wv[1]*tv[1] + wv[2]*tv[2] + wv[3]*tv[3]
               + wv[4]*tv[4] + wv[5]*tv[5] + wv[6]*tv[6] + wv[7]*tv[7];
    part += __shfl_xor(part, 1, 64);
    part += __shfl_xor(part, 2, 64);
    part += __shfl_xor(part, 4, 64);      // 8-group sums
    float other = __shfl_xor(part, 8, 64);
    float p = isA ? part : other;         // A-cosine
    float q = isA ? other : part;         // B-cosine
    float a1 = fmaf(p, 0.5f, 0.5f);
    float a2 = fmaf(q, 0.5f, 0.5f);
    r1 += a1; r2 += a2;
    uint2 ev = *(const uint2*)(tr + 128 + 8 * sub);
    float v0 = bf_lo(ev.x), v1 = bf_hi(ev.x), v2 = bf_lo(ev.y), v3 = bf_hi(ev.y);
    s1.x = fmaf(a1, v0, s1.x); s1.y = fmaf(a1, v1, s1.y);
    s1.z = fmaf(a1, v2, s1.z); s1.w = fmaf(a1, v3, s1.w);
    s2.x = fmaf(a2, v0, s2.x); s2.y = fmaf(a2, v1, s2.y);
    s2.z = fmaf(a2, v2, s2.z); s2.w = fmaf(a2, v3, s2.w);
  }
#pragma unroll
  for (int m = 16; m <= 32; m <<= 1){
    s1.x += __shfl_xor(s1.x, m, 64); s1.y += __shfl_xor(s1.y, m, 64);
    s1.z += __shfl_xor(s1.z, m, 64); s1.w += __shfl_xor(s1.w, m, 64);
    s2.x += __shfl_xor(s2.x, m, 64); s2.y += __shfl_xor(s2.y, m, 64);
    s2.z += __shfl_xor(s2.z, m, 64); s2.w += __shfl_xor(s2.w, m, 64);
    r1   += __shfl_xor(r1,   m, 64); r2   += __shfl_xor(r2,   m, 64);
  }
  float d1 = (r1 > 0.f) ? 1.f / r1 : 0.f;
  float d2 = (r2 > 0.f) ? 1.f / r2 : 0.f;
  if (slot == 0){
    int idx4 = w * 16 + sub;
    float4 gg = ((float4*)gnn_io)[idx4];
    uint2 it = inte_bf2[idx4];
    float4 em = ((const float4*)emb)[idx4];
    float4 nv;
    nv.x = gg.x + bf_lo(it.x) + em.x + d1 * s1.x + d2 * s2.x;
    nv.y = gg.y + bf_hi(it.x) + em.y + d1 * s1.y + d2 * s2.y;
    nv.z = gg.z + bf_lo(it.y) + em.z + d1 * s1.z + d2 * s2.z;
    nv.w = gg.w + bf_hi(it.y) + em.w + d1 * s1.w + d2 * s2.w;
    ((float4*)gnn_io)[idx4] = nv;
    float4 ac = ((float4*)acc)[idx4];
    ac.x += nv.x; ac.y += nv.y; ac.z += nv.z; ac.w += nv.w;
    ((float4*)acc)[idx4] = ac;
    if (write_next){
      float dw = dis[w];
      uint2 od;
      od.x = (unsigned)f2bf(dw * nv.x) | ((unsigned)f2bf(dw * nv.y) << 16);
      od.y = (unsigned)f2bf(dw * nv.z) | ((unsigned)f2bf(dw * nv.w) << 16);
      embd_next2[idx4] = od;   // premultiplied gather array for next spmm
      uint2 ob;
      ob.x = (unsigned)f2bf(nv.x) | ((unsigned)f2bf(nv.y) << 16);
      ob.y = (unsigned)f2bf(nv.z) | ((unsigned)f2bf(nv.w) << 16);
      *(uint2*)(rec_next + (size_t)w * RECB + 128 + 8 * sub) = ob;  // bf16 emb
    }
  }
}

extern "C" void kernel_launch(void* const* d_in, const int* in_sizes, int n_in,
                              void* d_out, int out_size, void* d_ws, size_t ws_size,
                              hipStream_t stream){
  const float* ue = (const float*)d_in[0];
  const float* ie = (const float*)d_in[1];
  const float* wu = (const float*)d_in[2];
  const float* wi = (const float*)d_in[3];
  const int* all_h = (const int*)d_in[4];
  const int* all_t = (const int*)d_in[5];
  float* acc = (float*)d_out;

  char* p = (char*)d_ws;
  auto take = [&](size_t bytes)->char*{
    char* r = p; p += (bytes + 255) & ~size_t(255); return r;
  };
  float*  embA  = (float*)take(sizeof(float) * N_NODES * DIM);
  float*  embB  = (float*)take(sizeof(float) * N_NODES * DIM);
  unsigned char* rec0 = (unsigned char*)take((size_t)N_NODES * RECB);
  unsigned char* rec1 = (unsigned char*)take((size_t)N_NODES * RECB);
  unsigned short* inte_bf = (unsigned short*)take(sizeof(short) * N_NODES * DIM);
  unsigned short* embd    = (unsigned short*)take(sizeof(short) * N_NODES * DIM);
  unsigned short* wbuf    = (unsigned short*)take(sizeof(short) * 2 * 32768);
  int*    t_csr = (int*)take(sizeof(int) * N_EDGES);
  float*  dis   = (float*)take(sizeof(float) * N_NODES);
  int*    deg   = (int*)take(sizeof(int) * N_NODES);
  int*    tmp   = (int*)take(sizeof(int) * N_NODES);
  int*    aux   = (int*)take(sizeof(int) * 1024);
  int*    rp    = (int*)take(sizeof(int) * (N_NODES + 1));
  int*    gcur  = (int*)take(sizeof(int) * NPART);
  if ((size_t)(p - (char*)d_ws) > ws_size) return;
  // staging (12 MB) aliases rec1 (38.4 MB): rec1 is first written by the
  // layer-0 adafuse epilogue, strictly after part1/part2 consume stg.
  // (rec0 carries k_embd0's layer-0 emb segment -> must NOT be aliased.)
  unsigned int* stg = (unsigned int*)rec1;

  const int ELEM_B  = (N_NODES * DIM + 255) / 256;
  const int ELEM4_B = (N_NODES * 16 + 255) / 256;
  const int NODEW_B = (N_NODES * 64 + 255) / 256;
  const int EDGE_B  = (N_EDGES + 255) / 256;
  const int NODE_B  = (N_NODES + 255) / 256;

  hipMemsetAsync(deg, 0, sizeof(int) * N_NODES, stream);
  k_init<<<ELEM_B, 256, 0, stream>>>(ue, ie, embA, acc);
  k_wprep<<<2, 256, 0, stream>>>(wu, wi, wbuf);
  k_deg<<<EDGE_B, 256, 0, stream>>>(all_h, deg);
  k_scan1<<<NODE_B, 256, 0, stream>>>(deg, tmp, aux);
  k_scan2<<<1, 1024, 0, stream>>>(aux, NODE_B);
  k_rowptr<<<NODE_B, 256, 0, stream>>>(tmp, deg, aux, rp, dis, gcur);
  k_embd0<<<ELEM4_B, 256, 0, stream>>>(embA, dis, (uint2*)embd, rec0);
  k_part1<<<NCHB, 256, 0, stream>>>(all_h, all_t, gcur, stg);
  k_part2<<<NPART, 256, 0, stream>>>(rp, stg, t_csr);

  float* eA = embA;
  float* eB = embB;
  unsigned char* recC = rec0;
  unsigned char* recN = rec1;
  for (int layer = 0; layer < 2; layer++){
    k_spmm_gnn<<<NODEW_B, 256, 0, stream>>>(rp, t_csr, dis, embd, eB, recC);
    k_intent_mfma<<<INT_B, 256, 0, stream>>>(wbuf, eA, inte_bf, recC);
    k_adafuse<<<NODEW_B, 256, 0, stream>>>(rp, t_csr, recC,
                                           (const uint2*)inte_bf,
                                           eA, dis, eB, acc,
                                           (uint2*)embd, recN,
                                           layer == 0 ? 1 : 0);
    float* t = eA; eA = eB; eB = t;
    unsigned char* tr = recC; recC = recN; recN = tr;
  }
}